// Round 1
// baseline (417.207 us; speedup 1.0000x reference)
//
#include <hip/hip_runtime.h>
#include <hip/hip_bf16.h>

// Problem constants
#define B_ 2
#define S_ 1024
#define I_ 512
#define C_ 32
#define EPS_ 1e-5f

// GEMM tiling
#define BM 128
#define BN 128
#define BK 32
#define NT (S_ / BK)   // 32 K-steps

typedef __attribute__((ext_vector_type(8))) short bf16x8;   // 8 bf16 = 4 VGPRs (MFMA A/B frag)
typedef __attribute__((ext_vector_type(4))) float f32x4;    // MFMA C/D frag

// ---------------------------------------------------------------------------
// Pass 0: LayerNorm over C + dual projection (a = mh@Wa.T+ba, b = mh@Wb.T+bb),
// written transposed as bf16: a_t[b][c][i][s], b_t[b][c][j][s] (GEMM row-major
// M x K with K = s contiguous). One thread per (b,i,s); s fastest within a
// block so the 2-byte stores coalesce to 128B per wave-store.
// Weights are read with wave-uniform addresses -> compiler scalarizes (s_load),
// so the 2048 FMAs/thread run near the VALU floor.
// ---------------------------------------------------------------------------
__global__ __launch_bounds__(256) void ln_proj_kernel(
    const float* __restrict__ m,
    const float* __restrict__ g, const float* __restrict__ beta,
    const float* __restrict__ Wa, const float* __restrict__ ba,
    const float* __restrict__ Wb, const float* __restrict__ bb,
    __hip_bfloat16* __restrict__ a_t, __hip_bfloat16* __restrict__ b_t)
{
    int tid = blockIdx.x * 256 + threadIdx.x;     // ((b*I + i)*S + s)
    int s  = tid & (S_ - 1);
    int bi = tid >> 10;
    int i  = bi & (I_ - 1);
    int b  = bi >> 9;

    const float* mp = m + (size_t)((b * S_ + s) * I_ + i) * C_;
    float x[C_];
#pragma unroll
    for (int v = 0; v < 8; ++v) {
        float4 t = reinterpret_cast<const float4*>(mp)[v];
        x[4*v+0] = t.x; x[4*v+1] = t.y; x[4*v+2] = t.z; x[4*v+3] = t.w;
    }

    float mu = 0.f;
#pragma unroll
    for (int c = 0; c < C_; ++c) mu += x[c];
    mu *= (1.f / C_);
    float var = 0.f;
#pragma unroll
    for (int c = 0; c < C_; ++c) { float d = x[c] - mu; var += d * d; }
    float rs = rsqrtf(var * (1.f / C_) + EPS_);
#pragma unroll
    for (int c = 0; c < C_; ++c) x[c] = (x[c] - mu) * rs * g[c] + beta[c];

    size_t ob = ((size_t)(b * C_) * I_ + i) * S_ + s;
#pragma unroll 4
    for (int c = 0; c < C_; ++c) {
        float accA = ba[c], accB = bb[c];
#pragma unroll
        for (int k = 0; k < C_; ++k) {
            accA = fmaf(Wa[c * C_ + k], x[k], accA);
            accB = fmaf(Wb[c * C_ + k], x[k], accB);
        }
        size_t off = ob + (size_t)c * (I_ * S_);
        a_t[off] = __float2bfloat16(accA);
        b_t[off] = __float2bfloat16(accB);
    }
}

// ---------------------------------------------------------------------------
// Pass 1: 64 independent GEMMs (one per (b,c)): outer[bc][i][j] = sum_s A[i,s]*B[j,s]
// m97-style structure: 128x128 tile, BK=32, 4 waves each computing a 64x64
// quadrant as 4x4 mfma_f32_16x16x32_bf16 frags. Double-buffered LDS staged
// via global_load_lds width=16 (linear [row][k] layout -> lane order matches).
// ---------------------------------------------------------------------------
__global__ __launch_bounds__(256) void opm_gemm_kernel(
    const __hip_bfloat16* __restrict__ a_t,
    const __hip_bfloat16* __restrict__ b_t,
    float* __restrict__ outer)
{
    __shared__ __align__(16) __hip_bfloat16 sA[2][BM * BK];  // 8 KiB per buf
    __shared__ __align__(16) __hip_bfloat16 sB[2][BN * BK];

    const int tid  = threadIdx.x;
    const int wave = tid >> 6;
    const int lane = tid & 63;
    const int blk  = blockIdx.x;
    const int bc   = blk >> 4;            // (b*C + c), 0..63
    const int tile = blk & 15;            // 4x4 output tiles per GEMM
    const int i0   = (tile >> 2) * BM;
    const int j0   = (tile & 3)  * BN;

    const __hip_bfloat16* Ap = a_t + ((size_t)bc * I_ + i0) * S_;
    const __hip_bfloat16* Bp = b_t + ((size_t)bc * I_ + j0) * S_;

    f32x4 acc[4][4];
#pragma unroll
    for (int mI = 0; mI < 4; ++mI)
#pragma unroll
        for (int nI = 0; nI < 4; ++nI)
            acc[mI][nI] = (f32x4){0.f, 0.f, 0.f, 0.f};

    const int wr = wave >> 1;      // wave row (0..1)
    const int wc = wave & 1;       // wave col (0..1)
    const int half = lane >> 4;    // k-group 0..3 (k = half*8 + e)
    const int lrow = lane & 15;    // row within 16x16 frag

    // staging: slot q = r*256 + tid maps to LDS byte q*16 and global
    // row = q>>2 (row stride S*2 bytes), byte-in-row = (q&3)*16.
    const int row_me = tid >> 2;
    const int kb_me  = (tid & 3) * 16;

#define STAGE(bufidx, t) do {                                                            \
        int s0b = (t) * (BK * 2);                                                        \
        const char* gA0 = (const char*)Ap + (size_t)row_me * (S_ * 2) + s0b + kb_me;     \
        const char* gB0 = (const char*)Bp + (size_t)row_me * (S_ * 2) + s0b + kb_me;     \
        char* lA = (char*)(&sA[bufidx][0]) + wave * 1024;                                \
        char* lB = (char*)(&sB[bufidx][0]) + wave * 1024;                                \
        __builtin_amdgcn_global_load_lds((const __attribute__((address_space(1))) void*)gA0,               \
                                         (__attribute__((address_space(3))) void*)lA, 16, 0, 0);           \
        __builtin_amdgcn_global_load_lds((const __attribute__((address_space(1))) void*)(gA0 + 64*(S_*2)), \
                                         (__attribute__((address_space(3))) void*)(lA + 4096), 16, 0, 0);  \
        __builtin_amdgcn_global_load_lds((const __attribute__((address_space(1))) void*)gB0,               \
                                         (__attribute__((address_space(3))) void*)lB, 16, 0, 0);           \
        __builtin_amdgcn_global_load_lds((const __attribute__((address_space(1))) void*)(gB0 + 64*(S_*2)), \
                                         (__attribute__((address_space(3))) void*)(lB + 4096), 16, 0, 0);  \
    } while (0)

    STAGE(0, 0);
    asm volatile("s_waitcnt vmcnt(0)" ::: "memory");
    __syncthreads();

#pragma unroll 2
    for (int t = 0; t < NT; ++t) {
        const int cur = t & 1;
        if (t + 1 < NT) STAGE(cur ^ 1, t + 1);   // prefetch next K-slab

        const __hip_bfloat16* lA = &sA[cur][0];
        const __hip_bfloat16* lB = &sB[cur][0];
        bf16x8 af[4], bfr[4];
#pragma unroll
        for (int mI = 0; mI < 4; ++mI)
            af[mI] = *reinterpret_cast<const bf16x8*>(lA + (wr*64 + mI*16 + lrow) * BK + half * 8);
#pragma unroll
        for (int nI = 0; nI < 4; ++nI)
            bfr[nI] = *reinterpret_cast<const bf16x8*>(lB + (wc*64 + nI*16 + lrow) * BK + half * 8);
#pragma unroll
        for (int mI = 0; mI < 4; ++mI)
#pragma unroll
            for (int nI = 0; nI < 4; ++nI)
                acc[mI][nI] = __builtin_amdgcn_mfma_f32_16x16x32_bf16(af[mI], bfr[nI], acc[mI][nI], 0, 0, 0);

        __syncthreads();   // compiler drains vmcnt+lgkmcnt here (buffers safe to swap)
    }
#undef STAGE

    // C/D layout (verified m89/m91): col = lane&15 (from B), row = (lane>>4)*4 + reg (from A)
    float* Op = outer + (size_t)bc * (I_ * I_);
#pragma unroll
    for (int mI = 0; mI < 4; ++mI) {
        int ii = i0 + wr*64 + mI*16 + half*4;
#pragma unroll
        for (int nI = 0; nI < 4; ++nI) {
            int jj = j0 + wc*64 + nI*16 + lrow;
#pragma unroll
            for (int r = 0; r < 4; ++r)
                Op[(size_t)(ii + r) * I_ + jj] = acc[mI][nI][r];
        }
    }
}

// ---------------------------------------------------------------------------
// Pass 2: out[b,i,j,c] = bo[c] + (1/S) * sum_c' Wo[c,c'] * outer[(b,c'),i,j]
// One thread per (b,i,j); j fastest -> per-c' loads fully coalesce; the 32
// outputs per thread are contiguous -> 8x float4 stores.
// ---------------------------------------------------------------------------
__global__ __launch_bounds__(256) void wo_kernel(
    const float* __restrict__ outer,
    const float* __restrict__ Wo, const float* __restrict__ bo,
    float* __restrict__ out)
{
    int tid = blockIdx.x * 256 + threadIdx.x;   // ((b*I + i)*J + j)
    int j  = tid & (I_ - 1);
    int bi = tid >> 9;
    int i  = bi & (I_ - 1);
    int b  = bi >> 9;

    const float* ip = outer + ((size_t)(b * C_) * I_ + i) * I_ + j;
    float v[C_];
#pragma unroll
    for (int c = 0; c < C_; ++c) v[c] = ip[(size_t)c * (I_ * I_)] * (1.f / S_);

    float o[C_];
#pragma unroll 4
    for (int c = 0; c < C_; ++c) {
        float acc = bo[c];
#pragma unroll
        for (int k = 0; k < C_; ++k) acc = fmaf(Wo[c * C_ + k], v[k], acc);
        o[c] = acc;
    }

    float* op = out + (size_t)tid * C_;
#pragma unroll
    for (int vv = 0; vv < 8; ++vv) {
        float4 t4 = { o[4*vv+0], o[4*vv+1], o[4*vv+2], o[4*vv+3] };
        reinterpret_cast<float4*>(op)[vv] = t4;
    }
}

// ---------------------------------------------------------------------------
extern "C" void kernel_launch(void* const* d_in, const int* in_sizes, int n_in,
                              void* d_out, int out_size, void* d_ws, size_t ws_size,
                              hipStream_t stream) {
    const float* m    = (const float*)d_in[0];
    const float* ln_g = (const float*)d_in[1];
    const float* ln_b = (const float*)d_in[2];
    const float* Wa   = (const float*)d_in[3];
    const float* ba   = (const float*)d_in[4];
    const float* Wb   = (const float*)d_in[5];
    const float* bb   = (const float*)d_in[6];
    const float* Wo   = (const float*)d_in[7];
    const float* bo   = (const float*)d_in[8];
    float* out = (float*)d_out;

    const size_t nAB = (size_t)B_ * C_ * I_ * S_;   // 33,554,432 elems (64 MiB bf16 each)
    const size_t nO  = (size_t)B_ * C_ * I_ * I_;   // 16,777,216 elems (64 MiB fp32)
    const size_t need = nAB * 2 * sizeof(__hip_bfloat16) + nO * sizeof(float); // 192 MiB
    if (ws_size < need) return;   // diagnostic: output stays zero -> ws too small

    __hip_bfloat16* a_t = (__hip_bfloat16*)d_ws;
    __hip_bfloat16* b_t = a_t + nAB;
    float* outer = (float*)(b_t + nAB);

    ln_proj_kernel<<<(B_ * S_ * I_) / 256, 256, 0, stream>>>(m, ln_g, ln_b, Wa, ba, Wb, bb, a_t, b_t);
    opm_gemm_kernel<<<B_ * C_ * 16, 256, 0, stream>>>(a_t, b_t, outer);
    wo_kernel<<<(B_ * I_ * I_) / 256, 256, 0, stream>>>(outer, Wo, bo, out);
}

// Round 2
// 416.422 us; speedup vs baseline: 1.0019x; 1.0019x over previous
//
#include <hip/hip_runtime.h>
#include <hip/hip_bf16.h>

// Problem constants
#define B_ 2
#define S_ 1024
#define I_ 512
#define C_ 32
#define EPS_ 1e-5f

// GEMM tiling
#define BM 128
#define BN 128
#define BK 32
#define NT (S_ / BK)   // 32 K-steps

typedef __attribute__((ext_vector_type(8))) short bf16x8;   // 8 bf16 = 4 VGPRs (MFMA A/B frag)
typedef __attribute__((ext_vector_type(4))) float f32x4;    // MFMA C/D frag

// ---------------------------------------------------------------------------
// Pass 0: LayerNorm over C + dual projection, written transposed as bf16:
// a_t[b][c][i][s], b_t[b][c][j][s].
//
// Round-1 problem: thread-per-(b,i,s) with s across lanes means each lane
// reads a private 128B row at 64KiB lane stride -> 64 scattered lines per
// load instr + power-of-2 channel/L2-set aliasing -> 310us at 2.7% HBM.
//
// Fix: block = (b, 4 i, 64 s). Stage the 32KiB input slab via contiguous
// float4 loads (per s-chunk: 4i x 32c = 512B contiguous), transpose through
// LDS (i-major rows, stride 36 floats = 16B aligned, bank-uniform), then
// thread = (i_l = wave, s_l = lane): LN + dual proj in fp32 regs; the 64
// bf16 stores per thread are 128B contiguous per wave-store (lane <-> s).
// ---------------------------------------------------------------------------
__global__ __launch_bounds__(256) void ln_proj_kernel(
    const float* __restrict__ m,
    const float* __restrict__ g, const float* __restrict__ beta,
    const float* __restrict__ Wa, const float* __restrict__ ba,
    const float* __restrict__ Wb, const float* __restrict__ bb,
    __hip_bfloat16* __restrict__ a_t, __hip_bfloat16* __restrict__ b_t)
{
    __shared__ __align__(16) float xs[256 * 36];   // 36 KiB: 256 rows, stride 36

    const int blk = blockIdx.x;                 // ((b*(I/4) + ig)*(S/64) + sg)
    const int sg = blk & 15;                    // S/64 = 16
    const int ig = (blk >> 4) & 127;            // I/4  = 128
    const int b  = blk >> 11;
    const int s0 = sg * 64;
    const int i0 = ig * 4;

    // ---- stage: 64 s-chunks x (4i x 32c floats = 512B contiguous each) ----
    const float* mb = m + ((size_t)(b * S_ + s0) * I_ + i0) * C_;
#pragma unroll
    for (int it = 0; it < 8; ++it) {
        int g4  = it * 256 + threadIdx.x;       // float4 index, 0..2047
        int s_l = g4 >> 5;                      // 32 float4 per s-chunk
        int rem = g4 & 31;                      // i_l*8 + c4
        float4 v = *reinterpret_cast<const float4*>(
            mb + (size_t)s_l * (I_ * C_) + rem * 4);
        int r = (rem >> 3) * 64 + s_l;          // i-major row index
        *reinterpret_cast<float4*>(&xs[r * 36 + (rem & 7) * 4]) = v;
    }
    __syncthreads();

    // ---- compute: one (i,s) row per thread; lane <-> s ----
    const int s_l = threadIdx.x & 63;
    const int i_l = threadIdx.x >> 6;           // = wave id (0..3)
    const float* row = &xs[(i_l * 64 + s_l) * 36];

    float x[C_];
#pragma unroll
    for (int v = 0; v < 8; ++v) {
        float4 t = reinterpret_cast<const float4*>(row)[v];
        x[4*v+0] = t.x; x[4*v+1] = t.y; x[4*v+2] = t.z; x[4*v+3] = t.w;
    }

    float mu = 0.f;
#pragma unroll
    for (int c = 0; c < C_; ++c) mu += x[c];
    mu *= (1.f / C_);
    float var = 0.f;
#pragma unroll
    for (int c = 0; c < C_; ++c) { float d = x[c] - mu; var += d * d; }
    float rs = rsqrtf(var * (1.f / C_) + EPS_);
#pragma unroll
    for (int c = 0; c < C_; ++c) x[c] = (x[c] - mu) * rs * g[c] + beta[c];

    // output base: a_t[(b*C + c)][i0+i_l][s0+s_l]
    size_t ob = ((size_t)(b * C_) * I_ + (i0 + i_l)) * S_ + s0 + s_l;
#pragma unroll 4
    for (int c = 0; c < C_; ++c) {
        float accA = ba[c], accB = bb[c];
#pragma unroll
        for (int k = 0; k < C_; ++k) {
            accA = fmaf(Wa[c * C_ + k], x[k], accA);
            accB = fmaf(Wb[c * C_ + k], x[k], accB);
        }
        size_t off = ob + (size_t)c * (I_ * S_);
        a_t[off] = __float2bfloat16(accA);      // 64 lanes: 128B contiguous
        b_t[off] = __float2bfloat16(accB);
    }
}

// ---------------------------------------------------------------------------
// Pass 1: 64 independent GEMMs (one per (b,c)): outer[bc][i][j] = sum_s A[i,s]*B[j,s]
// m97-style structure: 128x128 tile, BK=32, 4 waves each computing a 64x64
// quadrant as 4x4 mfma_f32_16x16x32_bf16 frags. Double-buffered LDS staged
// via global_load_lds width=16 (linear [row][k] layout -> lane order matches).
// ---------------------------------------------------------------------------
__global__ __launch_bounds__(256) void opm_gemm_kernel(
    const __hip_bfloat16* __restrict__ a_t,
    const __hip_bfloat16* __restrict__ b_t,
    float* __restrict__ outer)
{
    __shared__ __align__(16) __hip_bfloat16 sA[2][BM * BK];  // 8 KiB per buf
    __shared__ __align__(16) __hip_bfloat16 sB[2][BN * BK];

    const int tid  = threadIdx.x;
    const int wave = tid >> 6;
    const int lane = tid & 63;
    const int blk  = blockIdx.x;
    const int bc   = blk >> 4;            // (b*C + c), 0..63
    const int tile = blk & 15;            // 4x4 output tiles per GEMM
    const int i0   = (tile >> 2) * BM;
    const int j0   = (tile & 3)  * BN;

    const __hip_bfloat16* Ap = a_t + ((size_t)bc * I_ + i0) * S_;
    const __hip_bfloat16* Bp = b_t + ((size_t)bc * I_ + j0) * S_;

    f32x4 acc[4][4];
#pragma unroll
    for (int mI = 0; mI < 4; ++mI)
#pragma unroll
        for (int nI = 0; nI < 4; ++nI)
            acc[mI][nI] = (f32x4){0.f, 0.f, 0.f, 0.f};

    const int wr = wave >> 1;      // wave row (0..1)
    const int wc = wave & 1;       // wave col (0..1)
    const int half = lane >> 4;    // k-group 0..3 (k = half*8 + e)
    const int lrow = lane & 15;    // row within 16x16 frag

    // staging: slot q = r*256 + tid maps to LDS byte q*16 and global
    // row = q>>2 (row stride S*2 bytes), byte-in-row = (q&3)*16.
    const int row_me = tid >> 2;
    const int kb_me  = (tid & 3) * 16;

#define STAGE(bufidx, t) do {                                                            \
        int s0b = (t) * (BK * 2);                                                        \
        const char* gA0 = (const char*)Ap + (size_t)row_me * (S_ * 2) + s0b + kb_me;     \
        const char* gB0 = (const char*)Bp + (size_t)row_me * (S_ * 2) + s0b + kb_me;     \
        char* lA = (char*)(&sA[bufidx][0]) + wave * 1024;                                \
        char* lB = (char*)(&sB[bufidx][0]) + wave * 1024;                                \
        __builtin_amdgcn_global_load_lds((const __attribute__((address_space(1))) void*)gA0,               \
                                         (__attribute__((address_space(3))) void*)lA, 16, 0, 0);           \
        __builtin_amdgcn_global_load_lds((const __attribute__((address_space(1))) void*)(gA0 + 64*(S_*2)), \
                                         (__attribute__((address_space(3))) void*)(lA + 4096), 16, 0, 0);  \
        __builtin_amdgcn_global_load_lds((const __attribute__((address_space(1))) void*)gB0,               \
                                         (__attribute__((address_space(3))) void*)lB, 16, 0, 0);           \
        __builtin_amdgcn_global_load_lds((const __attribute__((address_space(1))) void*)(gB0 + 64*(S_*2)), \
                                         (__attribute__((address_space(3))) void*)(lB + 4096), 16, 0, 0);  \
    } while (0)

    STAGE(0, 0);
    asm volatile("s_waitcnt vmcnt(0)" ::: "memory");
    __syncthreads();

#pragma unroll 2
    for (int t = 0; t < NT; ++t) {
        const int cur = t & 1;
        if (t + 1 < NT) STAGE(cur ^ 1, t + 1);   // prefetch next K-slab

        const __hip_bfloat16* lA = &sA[cur][0];
        const __hip_bfloat16* lB = &sB[cur][0];
        bf16x8 af[4], bfr[4];
#pragma unroll
        for (int mI = 0; mI < 4; ++mI)
            af[mI] = *reinterpret_cast<const bf16x8*>(lA + (wr*64 + mI*16 + lrow) * BK + half * 8);
#pragma unroll
        for (int nI = 0; nI < 4; ++nI)
            bfr[nI] = *reinterpret_cast<const bf16x8*>(lB + (wc*64 + nI*16 + lrow) * BK + half * 8);
#pragma unroll
        for (int mI = 0; mI < 4; ++mI)
#pragma unroll
            for (int nI = 0; nI < 4; ++nI)
                acc[mI][nI] = __builtin_amdgcn_mfma_f32_16x16x32_bf16(af[mI], bfr[nI], acc[mI][nI], 0, 0, 0);

        __syncthreads();   // compiler drains vmcnt+lgkmcnt here (buffers safe to swap)
    }
#undef STAGE

    // C/D layout (verified m89/m91): col = lane&15 (from B), row = (lane>>4)*4 + reg (from A)
    float* Op = outer + (size_t)bc * (I_ * I_);
#pragma unroll
    for (int mI = 0; mI < 4; ++mI) {
        int ii = i0 + wr*64 + mI*16 + half*4;
#pragma unroll
        for (int nI = 0; nI < 4; ++nI) {
            int jj = j0 + wc*64 + nI*16 + lrow;
#pragma unroll
            for (int r = 0; r < 4; ++r)
                Op[(size_t)(ii + r) * I_ + jj] = acc[mI][nI][r];
        }
    }
}

// ---------------------------------------------------------------------------
// Pass 2: out[b,i,j,c] = bo[c] + (1/S) * sum_c' Wo[c,c'] * outer[(b,c'),i,j]
// One thread per (b,i,j); j fastest -> per-c' loads fully coalesce; the 32
// outputs per thread are contiguous -> 8x float4 stores.
// ---------------------------------------------------------------------------
__global__ __launch_bounds__(256) void wo_kernel(
    const float* __restrict__ outer,
    const float* __restrict__ Wo, const float* __restrict__ bo,
    float* __restrict__ out)
{
    int tid = blockIdx.x * 256 + threadIdx.x;   // ((b*I + i)*J + j)
    int j  = tid & (I_ - 1);
    int bi = tid >> 9;
    int i  = bi & (I_ - 1);
    int b  = bi >> 9;

    const float* ip = outer + ((size_t)(b * C_) * I_ + i) * I_ + j;
    float v[C_];
#pragma unroll
    for (int c = 0; c < C_; ++c) v[c] = ip[(size_t)c * (I_ * I_)] * (1.f / S_);

    float o[C_];
#pragma unroll 4
    for (int c = 0; c < C_; ++c) {
        float acc = bo[c];
#pragma unroll
        for (int k = 0; k < C_; ++k) acc = fmaf(Wo[c * C_ + k], v[k], acc);
        o[c] = acc;
    }

    float* op = out + (size_t)tid * C_;
#pragma unroll
    for (int vv = 0; vv < 8; ++vv) {
        float4 t4 = { o[4*vv+0], o[4*vv+1], o[4*vv+2], o[4*vv+3] };
        reinterpret_cast<float4*>(op)[vv] = t4;
    }
}

// ---------------------------------------------------------------------------
extern "C" void kernel_launch(void* const* d_in, const int* in_sizes, int n_in,
                              void* d_out, int out_size, void* d_ws, size_t ws_size,
                              hipStream_t stream) {
    const float* m    = (const float*)d_in[0];
    const float* ln_g = (const float*)d_in[1];
    const float* ln_b = (const float*)d_in[2];
    const float* Wa   = (const float*)d_in[3];
    const float* ba   = (const float*)d_in[4];
    const float* Wb   = (const float*)d_in[5];
    const float* bb   = (const float*)d_in[6];
    const float* Wo   = (const float*)d_in[7];
    const float* bo   = (const float*)d_in[8];
    float* out = (float*)d_out;

    const size_t nAB = (size_t)B_ * C_ * I_ * S_;   // 33,554,432 elems (64 MiB bf16 each)
    const size_t nO  = (size_t)B_ * C_ * I_ * I_;   // 16,777,216 elems (64 MiB fp32)
    const size_t need = nAB * 2 * sizeof(__hip_bfloat16) + nO * sizeof(float); // 192 MiB
    if (ws_size < need) return;   // diagnostic: output stays zero -> ws too small

    __hip_bfloat16* a_t = (__hip_bfloat16*)d_ws;
    __hip_bfloat16* b_t = a_t + nAB;
    float* outer = (float*)(b_t + nAB);

    ln_proj_kernel<<<B_ * (I_ / 4) * (S_ / 64), 256, 0, stream>>>(m, ln_g, ln_b, Wa, ba, Wb, bb, a_t, b_t);
    opm_gemm_kernel<<<B_ * C_ * 16, 256, 0, stream>>>(a_t, b_t, outer);
    wo_kernel<<<(B_ * I_ * I_) / 256, 256, 0, stream>>>(outer, Wo, bo, out);
}

// Round 3
// 228.451 us; speedup vs baseline: 1.8262x; 1.8228x over previous
//
#include <hip/hip_runtime.h>
#include <hip/hip_bf16.h>

// Problem constants
#define B_ 2
#define S_ 1024
#define I_ 512
#define C_ 32
#define EPS_ 1e-5f

// GEMM tiling
#define BM 128
#define BN 128
#define BK 32
#define NT (S_ / BK)   // 32 K-steps

typedef __attribute__((ext_vector_type(8))) short bf16x8;   // 8 bf16 = 4 VGPRs (MFMA A/B frag)
typedef __attribute__((ext_vector_type(4))) float f32x4;    // MFMA C/D frag

// ---------------------------------------------------------------------------
// Pass 0: LayerNorm over C + dual projection, written transposed as bf16:
// a_t[b][c][i][s], b_t[b][c][j][s].
//
// Round-2 post-mortem: read-path overhaul changed nothing (307us both rounds)
// -> bottleneck is the shared c-loop. VGPR=52 shows the compiler kept only
// one c-iteration live (in-loop stores let it retire accumulators): per c,
// 32 DEPENDENT FMAs fed by s_loads, lgkmcnt-serialized, ~90% stall at 43%
// occupancy. Fix: accA[32]/accB[32] as fully-unrolled register arrays with
// stores sunk after the loop -> 64 independent FMA chains, weight s_loads
// batched ahead. Pure-VALU floor ~27us.
// ---------------------------------------------------------------------------
__global__ __launch_bounds__(256) void ln_proj_kernel(
    const float* __restrict__ m,
    const float* __restrict__ g, const float* __restrict__ beta,
    const float* __restrict__ Wa, const float* __restrict__ ba,
    const float* __restrict__ Wb, const float* __restrict__ bb,
    __hip_bfloat16* __restrict__ a_t, __hip_bfloat16* __restrict__ b_t)
{
    __shared__ __align__(16) float xs[256 * 36];   // 36 KiB: 256 rows, stride 36

    const int blk = blockIdx.x;                 // ((b*(I/4) + ig)*(S/64) + sg)
    const int sg = blk & 15;                    // S/64 = 16
    const int ig = (blk >> 4) & 127;            // I/4  = 128
    const int b  = blk >> 11;
    const int s0 = sg * 64;
    const int i0 = ig * 4;

    // ---- stage: 64 s-chunks x (4i x 32c floats = 512B contiguous each) ----
    const float* mb = m + ((size_t)(b * S_ + s0) * I_ + i0) * C_;
#pragma unroll
    for (int it = 0; it < 8; ++it) {
        int g4  = it * 256 + threadIdx.x;       // float4 index, 0..2047
        int s_l = g4 >> 5;                      // 32 float4 per s-chunk
        int rem = g4 & 31;                      // i_l*8 + c4
        float4 v = *reinterpret_cast<const float4*>(
            mb + (size_t)s_l * (I_ * C_) + rem * 4);
        int r = (rem >> 3) * 64 + s_l;          // i-major row index
        *reinterpret_cast<float4*>(&xs[r * 36 + (rem & 7) * 4]) = v;
    }
    __syncthreads();

    // ---- compute: one (i,s) row per thread; lane <-> s ----
    const int s_l = threadIdx.x & 63;
    const int i_l = threadIdx.x >> 6;           // = wave id (0..3)
    const float* row = &xs[(i_l * 64 + s_l) * 36];

    float x[C_];
#pragma unroll
    for (int v = 0; v < 8; ++v) {
        float4 t = reinterpret_cast<const float4*>(row)[v];
        x[4*v+0] = t.x; x[4*v+1] = t.y; x[4*v+2] = t.z; x[4*v+3] = t.w;
    }

    float mu = 0.f;
#pragma unroll
    for (int c = 0; c < C_; ++c) mu += x[c];
    mu *= (1.f / C_);
    float var = 0.f;
#pragma unroll
    for (int c = 0; c < C_; ++c) { float d = x[c] - mu; var += d * d; }
    float rs = rsqrtf(var * (1.f / C_) + EPS_);
#pragma unroll
    for (int c = 0; c < C_; ++c) x[c] = (x[c] - mu) * rs * g[c] + beta[c];

    // ---- dual projection: 64 independent accumulator chains, full unroll ----
    float accA[C_], accB[C_];
#pragma unroll
    for (int c = 0; c < C_; ++c) { accA[c] = ba[c]; accB[c] = bb[c]; }
#pragma unroll
    for (int c = 0; c < C_; ++c) {
#pragma unroll
        for (int k = 0; k < C_; ++k) {
            accA[c] = fmaf(Wa[c * C_ + k], x[k], accA[c]);
            accB[c] = fmaf(Wb[c * C_ + k], x[k], accB[c]);
        }
    }

    // output base: a_t[(b*C + c)][i0+i_l][s0+s_l]; stores sunk after compute
    size_t ob = ((size_t)(b * C_) * I_ + (i0 + i_l)) * S_ + s0 + s_l;
#pragma unroll
    for (int c = 0; c < C_; ++c) {
        size_t off = ob + (size_t)c * (I_ * S_);
        a_t[off] = __float2bfloat16(accA[c]);   // 64 lanes: 128B contiguous
        b_t[off] = __float2bfloat16(accB[c]);
    }
}

// ---------------------------------------------------------------------------
// Pass 1: 64 independent GEMMs (one per (b,c)): outer[bc][i][j] = sum_s A[i,s]*B[j,s]
// m97-style structure: 128x128 tile, BK=32, 4 waves each computing a 64x64
// quadrant as 4x4 mfma_f32_16x16x32_bf16 frags. Double-buffered LDS staged
// via global_load_lds width=16 (linear [row][k] layout -> lane order matches).
// ---------------------------------------------------------------------------
__global__ __launch_bounds__(256) void opm_gemm_kernel(
    const __hip_bfloat16* __restrict__ a_t,
    const __hip_bfloat16* __restrict__ b_t,
    float* __restrict__ outer)
{
    __shared__ __align__(16) __hip_bfloat16 sA[2][BM * BK];  // 8 KiB per buf
    __shared__ __align__(16) __hip_bfloat16 sB[2][BN * BK];

    const int tid  = threadIdx.x;
    const int wave = tid >> 6;
    const int lane = tid & 63;
    const int blk  = blockIdx.x;
    const int bc   = blk >> 4;            // (b*C + c), 0..63
    const int tile = blk & 15;            // 4x4 output tiles per GEMM
    const int i0   = (tile >> 2) * BM;
    const int j0   = (tile & 3)  * BN;

    const __hip_bfloat16* Ap = a_t + ((size_t)bc * I_ + i0) * S_;
    const __hip_bfloat16* Bp = b_t + ((size_t)bc * I_ + j0) * S_;

    f32x4 acc[4][4];
#pragma unroll
    for (int mI = 0; mI < 4; ++mI)
#pragma unroll
        for (int nI = 0; nI < 4; ++nI)
            acc[mI][nI] = (f32x4){0.f, 0.f, 0.f, 0.f};

    const int wr = wave >> 1;      // wave row (0..1)
    const int wc = wave & 1;       // wave col (0..1)
    const int half = lane >> 4;    // k-group 0..3 (k = half*8 + e)
    const int lrow = lane & 15;    // row within 16x16 frag

    // staging: slot q = r*256 + tid maps to LDS byte q*16 and global
    // row = q>>2 (row stride S*2 bytes), byte-in-row = (q&3)*16.
    const int row_me = tid >> 2;
    const int kb_me  = (tid & 3) * 16;

#define STAGE(bufidx, t) do {                                                            \
        int s0b = (t) * (BK * 2);                                                        \
        const char* gA0 = (const char*)Ap + (size_t)row_me * (S_ * 2) + s0b + kb_me;     \
        const char* gB0 = (const char*)Bp + (size_t)row_me * (S_ * 2) + s0b + kb_me;     \
        char* lA = (char*)(&sA[bufidx][0]) + wave * 1024;                                \
        char* lB = (char*)(&sB[bufidx][0]) + wave * 1024;                                \
        __builtin_amdgcn_global_load_lds((const __attribute__((address_space(1))) void*)gA0,               \
                                         (__attribute__((address_space(3))) void*)lA, 16, 0, 0);           \
        __builtin_amdgcn_global_load_lds((const __attribute__((address_space(1))) void*)(gA0 + 64*(S_*2)), \
                                         (__attribute__((address_space(3))) void*)(lA + 4096), 16, 0, 0);  \
        __builtin_amdgcn_global_load_lds((const __attribute__((address_space(1))) void*)gB0,               \
                                         (__attribute__((address_space(3))) void*)lB, 16, 0, 0);           \
        __builtin_amdgcn_global_load_lds((const __attribute__((address_space(1))) void*)(gB0 + 64*(S_*2)), \
                                         (__attribute__((address_space(3))) void*)(lB + 4096), 16, 0, 0);  \
    } while (0)

    STAGE(0, 0);
    asm volatile("s_waitcnt vmcnt(0)" ::: "memory");
    __syncthreads();

#pragma unroll 2
    for (int t = 0; t < NT; ++t) {
        const int cur = t & 1;
        if (t + 1 < NT) STAGE(cur ^ 1, t + 1);   // prefetch next K-slab

        const __hip_bfloat16* lA = &sA[cur][0];
        const __hip_bfloat16* lB = &sB[cur][0];
        bf16x8 af[4], bfr[4];
#pragma unroll
        for (int mI = 0; mI < 4; ++mI)
            af[mI] = *reinterpret_cast<const bf16x8*>(lA + (wr*64 + mI*16 + lrow) * BK + half * 8);
#pragma unroll
        for (int nI = 0; nI < 4; ++nI)
            bfr[nI] = *reinterpret_cast<const bf16x8*>(lB + (wc*64 + nI*16 + lrow) * BK + half * 8);
#pragma unroll
        for (int mI = 0; mI < 4; ++mI)
#pragma unroll
            for (int nI = 0; nI < 4; ++nI)
                acc[mI][nI] = __builtin_amdgcn_mfma_f32_16x16x32_bf16(af[mI], bfr[nI], acc[mI][nI], 0, 0, 0);

        __syncthreads();   // compiler drains vmcnt+lgkmcnt here (buffers safe to swap)
    }
#undef STAGE

    // C/D layout (verified m89/m91): col = lane&15 (from B), row = (lane>>4)*4 + reg (from A)
    float* Op = outer + (size_t)bc * (I_ * I_);
#pragma unroll
    for (int mI = 0; mI < 4; ++mI) {
        int ii = i0 + wr*64 + mI*16 + half*4;
#pragma unroll
        for (int nI = 0; nI < 4; ++nI) {
            int jj = j0 + wc*64 + nI*16 + lrow;
#pragma unroll
            for (int r = 0; r < 4; ++r)
                Op[(size_t)(ii + r) * I_ + jj] = acc[mI][nI][r];
        }
    }
}

// ---------------------------------------------------------------------------
// Pass 2: out[b,i,j,c] = bo[c] + (1/S) * sum_c' Wo[c,c'] * outer[(b,c'),i,j]
// One thread per (b,i,j); j fastest -> per-c' loads fully coalesce; the 32
// outputs per thread are contiguous -> 8x float4 stores.
// ---------------------------------------------------------------------------
__global__ __launch_bounds__(256) void wo_kernel(
    const float* __restrict__ outer,
    const float* __restrict__ Wo, const float* __restrict__ bo,
    float* __restrict__ out)
{
    int tid = blockIdx.x * 256 + threadIdx.x;   // ((b*I + i)*J + j)
    int j  = tid & (I_ - 1);
    int bi = tid >> 9;
    int i  = bi & (I_ - 1);
    int b  = bi >> 9;

    const float* ip = outer + ((size_t)(b * C_) * I_ + i) * I_ + j;
    float v[C_];
#pragma unroll
    for (int c = 0; c < C_; ++c) v[c] = ip[(size_t)c * (I_ * I_)] * (1.f / S_);

    float o[C_];
#pragma unroll
    for (int c = 0; c < C_; ++c) {
        float acc = bo[c];
#pragma unroll
        for (int k = 0; k < C_; ++k) acc = fmaf(Wo[c * C_ + k], v[k], acc);
        o[c] = acc;
    }

    float* op = out + (size_t)tid * C_;
#pragma unroll
    for (int vv = 0; vv < 8; ++vv) {
        float4 t4 = { o[4*vv+0], o[4*vv+1], o[4*vv+2], o[4*vv+3] };
        reinterpret_cast<float4*>(op)[vv] = t4;
    }
}

// ---------------------------------------------------------------------------
extern "C" void kernel_launch(void* const* d_in, const int* in_sizes, int n_in,
                              void* d_out, int out_size, void* d_ws, size_t ws_size,
                              hipStream_t stream) {
    const float* m    = (const float*)d_in[0];
    const float* ln_g = (const float*)d_in[1];
    const float* ln_b = (const float*)d_in[2];
    const float* Wa   = (const float*)d_in[3];
    const float* ba   = (const float*)d_in[4];
    const float* Wb   = (const float*)d_in[5];
    const float* bb   = (const float*)d_in[6];
    const float* Wo   = (const float*)d_in[7];
    const float* bo   = (const float*)d_in[8];
    float* out = (float*)d_out;

    const size_t nAB = (size_t)B_ * C_ * I_ * S_;   // 33,554,432 elems (64 MiB bf16 each)
    const size_t nO  = (size_t)B_ * C_ * I_ * I_;   // 16,777,216 elems (64 MiB fp32)
    const size_t need = nAB * 2 * sizeof(__hip_bfloat16) + nO * sizeof(float); // 192 MiB
    if (ws_size < need) return;   // diagnostic: output stays zero -> ws too small

    __hip_bfloat16* a_t = (__hip_bfloat16*)d_ws;
    __hip_bfloat16* b_t = a_t + nAB;
    float* outer = (float*)(b_t + nAB);

    ln_proj_kernel<<<B_ * (I_ / 4) * (S_ / 64), 256, 0, stream>>>(m, ln_g, ln_b, Wa, ba, Wb, bb, a_t, b_t);
    opm_gemm_kernel<<<B_ * C_ * 16, 256, 0, stream>>>(a_t, b_t, outer);
    wo_kernel<<<(B_ * I_ * I_) / 256, 256, 0, stream>>>(outer, Wo, bo, out);
}

// Round 4
// 184.901 us; speedup vs baseline: 2.2564x; 1.2355x over previous
//
#include <hip/hip_runtime.h>
#include <hip/hip_bf16.h>

// Problem constants
#define B_ 2
#define S_ 1024
#define I_ 512
#define C_ 32
#define EPS_ 1e-5f

// GEMM tiling
#define BM 128
#define BN 128
#define BK 32
#define NT (S_ / BK)   // 32 K-steps

typedef __attribute__((ext_vector_type(8))) short bf16x8;   // 8 bf16 = 4 VGPRs (MFMA A/B frag)
typedef __attribute__((ext_vector_type(4))) short bf16x4;   // 4 bf16 = 8 B
typedef __attribute__((ext_vector_type(4))) float f32x4;    // MFMA C/D frag

static __device__ __forceinline__ short f2bf(float f) {
    union { __hip_bfloat16 h; short s; } u;
    u.h = __float2bfloat16(f);
    return u.s;
}

// ---------------------------------------------------------------------------
// Pass 0: LayerNorm over C + dual projection via MFMA, written transposed as
// bf16: a_t[b][c][i][s], b_t[b][c][j][s].
//
// Round-3 post-mortem: c-loop is VALU-issue-bound (2048 scalar FMAs/thread,
// VALUBusy 57%, 121us). The projection is a (256 pos x 32k) x (32k x 64c)
// matmul per block -> MFMA (Guideline 10). Per wave: 16 mfma_16x16x32_bf16
// replace 2048 VALU FMAs.
//
// Phases: (1) coalesced stage of m slab -> xs (fp32, 36KiB, bank-uniform)
// (2) per-thread row read + LN in fp32 regs (3) pack bf16, write LDS in
// MFMA-frag-linear order [pt][kslice][lo] (bank-uniform 8/bank)
// (4) 4x ds_read_b128 A-frags (pure linear), 16 MFMA against in-reg Wa/Wb
// B-frags (5) bias + transpose D (c-on-lanes -> s-on-lanes) through padded
// LDS (stride 72, ~2-way banks) overlaying dead xs (6) 128B-contiguous
// bf16x8 global stores. 2 barriers; LDS 52KiB -> 3 blocks/CU.
// ---------------------------------------------------------------------------
__global__ __launch_bounds__(256) void ln_proj_kernel(
    const float* __restrict__ m,
    const float* __restrict__ g, const float* __restrict__ beta,
    const float* __restrict__ Wa, const float* __restrict__ ba,
    const float* __restrict__ Wb, const float* __restrict__ bb,
    __hip_bfloat16* __restrict__ a_t, __hip_bfloat16* __restrict__ b_t)
{
    __shared__ __align__(16) char lds_raw[53248];   // 52 KiB
    float* xs = reinterpret_cast<float*>(lds_raw);                       // [0, 36864)
    __hip_bfloat16* mhf = reinterpret_cast<__hip_bfloat16*>(lds_raw + 36864); // 16 KiB
    __hip_bfloat16* trb = reinterpret_cast<__hip_bfloat16*>(lds_raw);    // overlays xs (dead)

    const int tid  = threadIdx.x;
    const int lane = tid & 63;
    const int w    = tid >> 6;       // wave = i_l
    const int lo   = lane & 15;
    const int hi   = lane >> 4;

    const int blk = blockIdx.x;                 // ((b*(I/4) + ig)*(S/64) + sg)
    const int sg = blk & 15;
    const int ig = (blk >> 4) & 127;
    const int b  = blk >> 11;
    const int s0 = sg * 64;
    const int i0 = ig * 4;

    // ---- B-frags: Wa/Wb rows as bf16x8 (lane l: W[c=ct*16+(l&15)][k=(l>>4)*8+e]) ----
    bf16x8 bw[4];
    float biasv[4];
#pragma unroll
    for (int f = 0; f < 4; ++f) {
        const float* Wsrc = (f & 2) ? Wb : Wa;
        const float* bsrc = (f & 2) ? bb : ba;
        int c = (f & 1) * 16 + lo;
        const float* src = Wsrc + c * C_ + hi * 8;
        float4 u0 = *reinterpret_cast<const float4*>(src);
        float4 u1 = *reinterpret_cast<const float4*>(src + 4);
        bf16x8 ch;
        ch[0] = f2bf(u0.x); ch[1] = f2bf(u0.y); ch[2] = f2bf(u0.z); ch[3] = f2bf(u0.w);
        ch[4] = f2bf(u1.x); ch[5] = f2bf(u1.y); ch[6] = f2bf(u1.z); ch[7] = f2bf(u1.w);
        bw[f] = ch;
        biasv[f] = bsrc[c];
    }

    // ---- stage: 64 s-chunks x (4i x 32c floats = 512B contiguous each) ----
    const float* mb = m + ((size_t)(b * S_ + s0) * I_ + i0) * C_;
#pragma unroll
    for (int it = 0; it < 8; ++it) {
        int g4  = it * 256 + tid;
        int s_l = g4 >> 5;
        int rem = g4 & 31;
        float4 v = *reinterpret_cast<const float4*>(
            mb + (size_t)s_l * (I_ * C_) + rem * 4);
        int r = (rem >> 3) * 64 + s_l;
        *reinterpret_cast<float4*>(&xs[r * 36 + (rem & 7) * 4]) = v;
    }
    __syncthreads();

    // ---- LN: one (i,s) row per thread (i = w, s = lane) ----
    const float* row = &xs[(w * 64 + lane) * 36];
    float x[C_];
#pragma unroll
    for (int v = 0; v < 8; ++v) {
        float4 t = reinterpret_cast<const float4*>(row)[v];
        x[4*v+0] = t.x; x[4*v+1] = t.y; x[4*v+2] = t.z; x[4*v+3] = t.w;
    }
    float mu = 0.f;
#pragma unroll
    for (int c = 0; c < C_; ++c) mu += x[c];
    mu *= (1.f / C_);
    float var = 0.f;
#pragma unroll
    for (int c = 0; c < C_; ++c) { float d = x[c] - mu; var += d * d; }
    float rs = rsqrtf(var * (1.f / C_) + EPS_);
#pragma unroll
    for (int c = 0; c < C_; ++c) x[c] = (x[c] - mu) * rs * g[c] + beta[c];

    // ---- pack bf16, write frag-linear: elem = pt*512 + kslice*128 + lo*8 ----
    const int pt = w * 4 + hi;        // pos-tile of this thread's row
#pragma unroll
    for (int h2 = 0; h2 < 4; ++h2) {
        bf16x8 ch;
#pragma unroll
        for (int e = 0; e < 8; ++e) ch[e] = f2bf(x[h2 * 8 + e]);
        *reinterpret_cast<bf16x8*>(mhf + pt * 512 + h2 * 128 + lo * 8) = ch;
    }
    __syncthreads();

    // ---- A-frags (pure linear reads) + 16 MFMA ----
    f32x4 d[4][4];
#pragma unroll
    for (int q = 0; q < 4; ++q) {
        bf16x8 af = *reinterpret_cast<const bf16x8*>(mhf + (w * 4 + q) * 512 + lane * 8);
#pragma unroll
        for (int f = 0; f < 4; ++f)
            d[q][f] = __builtin_amdgcn_mfma_f32_16x16x32_bf16(
                af, bw[f], (f32x4){0.f, 0.f, 0.f, 0.f}, 0, 0, 0);
    }

    // ---- bias + transpose through padded LDS (stride 72 elems, overlays xs) ----
    __hip_bfloat16* trw = trb + w * 4608;     // per-wave 9216 B region
#pragma unroll
    for (int q = 0; q < 4; ++q)
#pragma unroll
        for (int f = 0; f < 4; ++f) {
            bf16x4 v4;
#pragma unroll
            for (int r = 0; r < 4; ++r) v4[r] = f2bf(d[q][f][r] + biasv[f]);
            int c = (f & 1) * 16 + lo;        // channel within projection
            int s = q * 16 + hi * 4;          // s within the wave's 64-s window
            *reinterpret_cast<bf16x4*>(trw + (f >> 1) * 2304 + c * 72 + s) = v4;
        }

    // ---- read s-contiguous rows (own-wave data) and store 128B-coalesced ----
#pragma unroll
    for (int p = 0; p < 2; ++p) {
        __hip_bfloat16* outp = p ? b_t : a_t;
#pragma unroll
        for (int cg = 0; cg < 4; ++cg) {
            int c  = cg * 8 + (lane >> 3);
            int s8 = (lane & 7) * 8;
            bf16x8 vv = *reinterpret_cast<const bf16x8*>(trw + p * 2304 + c * 72 + s8);
            size_t off = ((size_t)(b * C_ + c) * I_ + (i0 + w)) * S_ + s0 + s8;
            *reinterpret_cast<bf16x8*>(outp + off) = vv;
        }
    }
}

// ---------------------------------------------------------------------------
// Pass 1: 64 independent GEMMs (one per (b,c)): outer[bc][i][j] = sum_s A[i,s]*B[j,s]
// m97-style structure: 128x128 tile, BK=32, 4 waves each computing a 64x64
// quadrant as 4x4 mfma_f32_16x16x32_bf16 frags. Double-buffered LDS staged
// via global_load_lds width=16 (linear [row][k] layout -> lane order matches).
// ---------------------------------------------------------------------------
__global__ __launch_bounds__(256) void opm_gemm_kernel(
    const __hip_bfloat16* __restrict__ a_t,
    const __hip_bfloat16* __restrict__ b_t,
    float* __restrict__ outer)
{
    __shared__ __align__(16) __hip_bfloat16 sA[2][BM * BK];  // 8 KiB per buf
    __shared__ __align__(16) __hip_bfloat16 sB[2][BN * BK];

    const int tid  = threadIdx.x;
    const int wave = tid >> 6;
    const int lane = tid & 63;
    const int blk  = blockIdx.x;
    const int bc   = blk >> 4;            // (b*C + c), 0..63
    const int tile = blk & 15;            // 4x4 output tiles per GEMM
    const int i0   = (tile >> 2) * BM;
    const int j0   = (tile & 3)  * BN;

    const __hip_bfloat16* Ap = a_t + ((size_t)bc * I_ + i0) * S_;
    const __hip_bfloat16* Bp = b_t + ((size_t)bc * I_ + j0) * S_;

    f32x4 acc[4][4];
#pragma unroll
    for (int mI = 0; mI < 4; ++mI)
#pragma unroll
        for (int nI = 0; nI < 4; ++nI)
            acc[mI][nI] = (f32x4){0.f, 0.f, 0.f, 0.f};

    const int wr = wave >> 1;      // wave row (0..1)
    const int wc = wave & 1;       // wave col (0..1)
    const int half = lane >> 4;    // k-group 0..3 (k = half*8 + e)
    const int lrow = lane & 15;    // row within 16x16 frag

    // staging: slot q = r*256 + tid maps to LDS byte q*16 and global
    // row = q>>2 (row stride S*2 bytes), byte-in-row = (q&3)*16.
    const int row_me = tid >> 2;
    const int kb_me  = (tid & 3) * 16;

#define STAGE(bufidx, t) do {                                                            \
        int s0b = (t) * (BK * 2);                                                        \
        const char* gA0 = (const char*)Ap + (size_t)row_me * (S_ * 2) + s0b + kb_me;     \
        const char* gB0 = (const char*)Bp + (size_t)row_me * (S_ * 2) + s0b + kb_me;     \
        char* lA = (char*)(&sA[bufidx][0]) + wave * 1024;                                \
        char* lB = (char*)(&sB[bufidx][0]) + wave * 1024;                                \
        __builtin_amdgcn_global_load_lds((const __attribute__((address_space(1))) void*)gA0,               \
                                         (__attribute__((address_space(3))) void*)lA, 16, 0, 0);           \
        __builtin_amdgcn_global_load_lds((const __attribute__((address_space(1))) void*)(gA0 + 64*(S_*2)), \
                                         (__attribute__((address_space(3))) void*)(lA + 4096), 16, 0, 0);  \
        __builtin_amdgcn_global_load_lds((const __attribute__((address_space(1))) void*)gB0,               \
                                         (__attribute__((address_space(3))) void*)lB, 16, 0, 0);           \
        __builtin_amdgcn_global_load_lds((const __attribute__((address_space(1))) void*)(gB0 + 64*(S_*2)), \
                                         (__attribute__((address_space(3))) void*)(lB + 4096), 16, 0, 0);  \
    } while (0)

    STAGE(0, 0);
    asm volatile("s_waitcnt vmcnt(0)" ::: "memory");
    __syncthreads();

#pragma unroll 2
    for (int t = 0; t < NT; ++t) {
        const int cur = t & 1;
        if (t + 1 < NT) STAGE(cur ^ 1, t + 1);   // prefetch next K-slab

        const __hip_bfloat16* lA = &sA[cur][0];
        const __hip_bfloat16* lB = &sB[cur][0];
        bf16x8 af[4], bfr[4];
#pragma unroll
        for (int mI = 0; mI < 4; ++mI)
            af[mI] = *reinterpret_cast<const bf16x8*>(lA + (wr*64 + mI*16 + lrow) * BK + half * 8);
#pragma unroll
        for (int nI = 0; nI < 4; ++nI)
            bfr[nI] = *reinterpret_cast<const bf16x8*>(lB + (wc*64 + nI*16 + lrow) * BK + half * 8);
#pragma unroll
        for (int mI = 0; mI < 4; ++mI)
#pragma unroll
            for (int nI = 0; nI < 4; ++nI)
                acc[mI][nI] = __builtin_amdgcn_mfma_f32_16x16x32_bf16(af[mI], bfr[nI], acc[mI][nI], 0, 0, 0);

        __syncthreads();   // compiler drains vmcnt+lgkmcnt here (buffers safe to swap)
    }
#undef STAGE

    // C/D layout (verified m89/m91): col = lane&15 (from B), row = (lane>>4)*4 + reg (from A)
    float* Op = outer + (size_t)bc * (I_ * I_);
#pragma unroll
    for (int mI = 0; mI < 4; ++mI) {
        int ii = i0 + wr*64 + mI*16 + half*4;
#pragma unroll
        for (int nI = 0; nI < 4; ++nI) {
            int jj = j0 + wc*64 + nI*16 + lrow;
#pragma unroll
            for (int r = 0; r < 4; ++r)
                Op[(size_t)(ii + r) * I_ + jj] = acc[mI][nI][r];
        }
    }
}

// ---------------------------------------------------------------------------
// Pass 2: out[b,i,j,c] = bo[c] + (1/S) * sum_c' Wo[c,c'] * outer[(b,c'),i,j]
// One thread per (b,i,j); j fastest -> per-c' loads fully coalesce; the 32
// outputs per thread are contiguous -> 8x float4 stores.
// ---------------------------------------------------------------------------
__global__ __launch_bounds__(256) void wo_kernel(
    const float* __restrict__ outer,
    const float* __restrict__ Wo, const float* __restrict__ bo,
    float* __restrict__ out)
{
    int tid = blockIdx.x * 256 + threadIdx.x;   // ((b*I + i)*J + j)
    int j  = tid & (I_ - 1);
    int bi = tid >> 9;
    int i  = bi & (I_ - 1);
    int b  = bi >> 9;

    const float* ip = outer + ((size_t)(b * C_) * I_ + i) * I_ + j;
    float v[C_];
#pragma unroll
    for (int c = 0; c < C_; ++c) v[c] = ip[(size_t)c * (I_ * I_)] * (1.f / S_);

    float o[C_];
#pragma unroll
    for (int c = 0; c < C_; ++c) {
        float acc = bo[c];
#pragma unroll
        for (int k = 0; k < C_; ++k) acc = fmaf(Wo[c * C_ + k], v[k], acc);
        o[c] = acc;
    }

    float* op = out + (size_t)tid * C_;
#pragma unroll
    for (int vv = 0; vv < 8; ++vv) {
        float4 t4 = { o[4*vv+0], o[4*vv+1], o[4*vv+2], o[4*vv+3] };
        reinterpret_cast<float4*>(op)[vv] = t4;
    }
}

// ---------------------------------------------------------------------------
extern "C" void kernel_launch(void* const* d_in, const int* in_sizes, int n_in,
                              void* d_out, int out_size, void* d_ws, size_t ws_size,
                              hipStream_t stream) {
    const float* m    = (const float*)d_in[0];
    const float* ln_g = (const float*)d_in[1];
    const float* ln_b = (const float*)d_in[2];
    const float* Wa   = (const float*)d_in[3];
    const float* ba   = (const float*)d_in[4];
    const float* Wb   = (const float*)d_in[5];
    const float* bb   = (const float*)d_in[6];
    const float* Wo   = (const float*)d_in[7];
    const float* bo   = (const float*)d_in[8];
    float* out = (float*)d_out;

    const size_t nAB = (size_t)B_ * C_ * I_ * S_;   // 33,554,432 elems (64 MiB bf16 each)
    const size_t nO  = (size_t)B_ * C_ * I_ * I_;   // 16,777,216 elems (64 MiB fp32)
    const size_t need = nAB * 2 * sizeof(__hip_bfloat16) + nO * sizeof(float); // 192 MiB
    if (ws_size < need) return;   // diagnostic: output stays zero -> ws too small

    __hip_bfloat16* a_t = (__hip_bfloat16*)d_ws;
    __hip_bfloat16* b_t = a_t + nAB;
    float* outer = (float*)(b_t + nAB);

    ln_proj_kernel<<<B_ * (I_ / 4) * (S_ / 64), 256, 0, stream>>>(m, ln_g, ln_b, Wa, ba, Wb, bb, a_t, b_t);
    opm_gemm_kernel<<<B_ * C_ * 16, 256, 0, stream>>>(a_t, b_t, outer);
    wo_kernel<<<(B_ * I_ * I_) / 256, 256, 0, stream>>>(outer, Wo, bo, out);
}

// Round 5
// 177.289 us; speedup vs baseline: 2.3533x; 1.0429x over previous
//
#include <hip/hip_runtime.h>
#include <hip/hip_bf16.h>

// Problem constants
#define B_ 2
#define S_ 1024
#define I_ 512
#define C_ 32
#define EPS_ 1e-5f

// GEMM tiling
#define BM 128
#define BN 128
#define BK 32
#define NT (S_ / BK)   // 32 K-steps

typedef __attribute__((ext_vector_type(8))) short bf16x8;   // 8 bf16 = 4 VGPRs (MFMA A/B frag)
typedef __attribute__((ext_vector_type(4))) short bf16x4;   // 4 bf16 = 8 B
typedef __attribute__((ext_vector_type(4))) float f32x4;    // MFMA C/D frag

static __device__ __forceinline__ short f2bf(float f) {
    union { __hip_bfloat16 h; short s; } u;
    u.h = __float2bfloat16(f);
    return u.s;
}

// ---------------------------------------------------------------------------
// Pass 0 (v4): fused stage+LN via lane-group shuffles + MFMA projection.
//
// Round-4 post-mortem: v3 at 86us was LDS/latency-bound (52KiB LDS -> 3
// blocks/CU, occ 17%, 1.57M bank conflicts, 8-way-conflicted fp32 row
// re-reads). v4 deletes the xs fp32 buffer: each lane loads float4 = 4 c's
// of one (i,s) row; the row's 8 slots live in 8 CONSECUTIVE lanes, so
// (sum x, sum x^2) reduce = 3 shfl_xor rounds; lane normalizes its 4 c's
// and writes bf16x4 DIRECTLY in MFMA-frag order to mhf. One barrier, then
// per-wave: 4 ds_read_b128 A-frags, 16 MFMA vs in-reg Wa/Wb B-frags, bias,
// transpose through a time-shared per-wave padded buffer (stride 72),
// 128B-coalesced bf16x8 stores. LDS 34KiB -> 4 blocks/CU.
// ---------------------------------------------------------------------------
__global__ __launch_bounds__(256) void ln_proj_kernel(
    const float* __restrict__ m,
    const float* __restrict__ g, const float* __restrict__ beta,
    const float* __restrict__ Wa, const float* __restrict__ ba,
    const float* __restrict__ Wb, const float* __restrict__ bb,
    __hip_bfloat16* __restrict__ a_t, __hip_bfloat16* __restrict__ b_t)
{
    __shared__ __align__(16) __hip_bfloat16 mhf[8192];      // 16 KiB frag-linear mh
    __shared__ __align__(16) __hip_bfloat16 trb[4 * 2304];  // 18 KiB transpose, time-shared A/B

    const int tid  = threadIdx.x;
    const int lane = tid & 63;
    const int w    = tid >> 6;
    const int lo   = lane & 15;
    const int hi   = lane >> 4;

    const int blk = blockIdx.x;                 // ((b*(I/4) + ig)*(S/64) + sg)
    const int sg = blk & 15;
    const int ig = (blk >> 4) & 127;
    const int b  = blk >> 11;
    const int s0 = sg * 64;
    const int i0 = ig * 4;

    // ---- B-frags: Wa/Wb rows as bf16x8 (lane l: W[c=(f&1)*16+lo][k=hi*8+e]) ----
    bf16x8 bw[4];
    float biasv[4];
#pragma unroll
    for (int f = 0; f < 4; ++f) {
        const float* Wsrc = (f & 2) ? Wb : Wa;
        const float* bsrc = (f & 2) ? bb : ba;
        int c = (f & 1) * 16 + lo;
        const float* src = Wsrc + c * C_ + hi * 8;
        float4 u0 = *reinterpret_cast<const float4*>(src);
        float4 u1 = *reinterpret_cast<const float4*>(src + 4);
        bf16x8 ch;
        ch[0] = f2bf(u0.x); ch[1] = f2bf(u0.y); ch[2] = f2bf(u0.z); ch[3] = f2bf(u0.w);
        ch[4] = f2bf(u1.x); ch[5] = f2bf(u1.y); ch[6] = f2bf(u1.z); ch[7] = f2bf(u1.w);
        bw[f] = ch;
        biasv[f] = bsrc[c];
    }

    // ---- fused stage + LN ----
    // lane decomposition within each iteration: slot = lane&7 (c-range slot*4..+3),
    // i_l = (lane>>3)&3; row (i_l, s_l) spans 8 consecutive lanes.
    const int slot = lane & 7;
    const int i_l  = (lane >> 3) & 3;
    const float4 gg = *reinterpret_cast<const float4*>(g + slot * 4);
    const float4 gb = *reinterpret_cast<const float4*>(beta + slot * 4);

    const float* mb = m + ((size_t)(b * S_ + s0) * I_ + i0) * C_;
#pragma unroll
    for (int it = 0; it < 8; ++it) {
        int g4  = it * 256 + tid;
        int s_l = g4 >> 5;                      // 0..63
        float4 v = *reinterpret_cast<const float4*>(
            mb + (size_t)s_l * (I_ * C_) + (i_l * 8 + slot) * 4);

        float s1 = v.x + v.y + v.z + v.w;
        float s2 = v.x*v.x + v.y*v.y + v.z*v.z + v.w*v.w;
#pragma unroll
        for (int d = 1; d < 8; d <<= 1) {
            s1 += __shfl_xor(s1, d, 64);
            s2 += __shfl_xor(s2, d, 64);
        }
        float mu  = s1 * (1.f / C_);
        float var = s2 * (1.f / C_) - mu * mu;
        float rs  = rsqrtf(var + EPS_);

        bf16x4 pk;
        pk[0] = f2bf((v.x - mu) * rs * gg.x + gb.x);
        pk[1] = f2bf((v.y - mu) * rs * gg.y + gb.y);
        pk[2] = f2bf((v.z - mu) * rs * gg.z + gb.z);
        pk[3] = f2bf((v.w - mu) * rs * gg.w + gb.w);

        // frag-linear: pos p = i_l*64 + s_l, k0 = slot*4
        int p   = i_l * 64 + s_l;
        int idx = (p >> 4) * 512 + (slot >> 1) * 128 + (p & 15) * 8 + (slot & 1) * 4;
        *reinterpret_cast<bf16x4*>(mhf + idx) = pk;
    }
    __syncthreads();

    // ---- A-frags (linear reads, own quarter) + 16 MFMA ----
    f32x4 d[4][4];
#pragma unroll
    for (int q = 0; q < 4; ++q) {
        bf16x8 af = *reinterpret_cast<const bf16x8*>(mhf + (w * 4 + q) * 512 + lane * 8);
#pragma unroll
        for (int f = 0; f < 4; ++f)
            d[q][f] = __builtin_amdgcn_mfma_f32_16x16x32_bf16(
                af, bw[f], (f32x4){0.f, 0.f, 0.f, 0.f}, 0, 0, 0);
    }

    // ---- bias + transpose + store, time-shared per projection (wave-private) ----
    __hip_bfloat16* trw = trb + w * 2304;
#pragma unroll
    for (int p = 0; p < 2; ++p) {
#pragma unroll
        for (int q = 0; q < 4; ++q)
#pragma unroll
            for (int fh = 0; fh < 2; ++fh) {
                int f = p * 2 + fh;
                bf16x4 v4;
#pragma unroll
                for (int r = 0; r < 4; ++r) v4[r] = f2bf(d[q][f][r] + biasv[f]);
                int c = fh * 16 + lo;
                int s = q * 16 + hi * 4;
                *reinterpret_cast<bf16x4*>(trw + c * 72 + s) = v4;
            }
        __hip_bfloat16* outp = p ? b_t : a_t;
#pragma unroll
        for (int cg = 0; cg < 4; ++cg) {
            int c  = cg * 8 + (lane >> 3);
            int s8 = (lane & 7) * 8;
            bf16x8 vv = *reinterpret_cast<const bf16x8*>(trw + c * 72 + s8);
            size_t off = ((size_t)(b * C_ + c) * I_ + (i0 + w)) * S_ + s0 + s8;
            *reinterpret_cast<bf16x8*>(outp + off) = vv;   // 128B/wave contiguous
        }
    }
}

// ---------------------------------------------------------------------------
// Pass 1: 64 independent GEMMs (one per (b,c)): outer[bc][i][j] = sum_s A[i,s]*B[j,s]
// m97-style structure + T1 chunked XCD swizzle: 128 consecutive logical
// blocks (= 8 whole GEMMs, 2 MiB of panels) per XCD -> panel re-reads become
// XCD-local L2 hits instead of cross-XCD HBM/L3 re-fetch.
// ---------------------------------------------------------------------------
__global__ __launch_bounds__(256) void opm_gemm_kernel(
    const __hip_bfloat16* __restrict__ a_t,
    const __hip_bfloat16* __restrict__ b_t,
    float* __restrict__ outer)
{
    __shared__ __align__(16) __hip_bfloat16 sA[2][BM * BK];  // 8 KiB per buf
    __shared__ __align__(16) __hip_bfloat16 sB[2][BN * BK];

    const int tid  = threadIdx.x;
    const int wave = tid >> 6;
    const int lane = tid & 63;
    // T1: grid = 1024 (divisible by 8 XCDs) -> bijective chunked swizzle
    const int swz  = (blockIdx.x & 7) * 128 + (blockIdx.x >> 3);
    const int bc   = swz >> 4;            // (b*C + c), 0..63
    const int tile = swz & 15;            // 4x4 output tiles per GEMM
    const int i0   = (tile >> 2) * BM;
    const int j0   = (tile & 3)  * BN;

    const __hip_bfloat16* Ap = a_t + ((size_t)bc * I_ + i0) * S_;
    const __hip_bfloat16* Bp = b_t + ((size_t)bc * I_ + j0) * S_;

    f32x4 acc[4][4];
#pragma unroll
    for (int mI = 0; mI < 4; ++mI)
#pragma unroll
        for (int nI = 0; nI < 4; ++nI)
            acc[mI][nI] = (f32x4){0.f, 0.f, 0.f, 0.f};

    const int wr = wave >> 1;      // wave row (0..1)
    const int wc = wave & 1;       // wave col (0..1)
    const int half = lane >> 4;    // k-group 0..3 (k = half*8 + e)
    const int lrow = lane & 15;    // row within 16x16 frag

    const int row_me = tid >> 2;
    const int kb_me  = (tid & 3) * 16;

#define STAGE(bufidx, t) do {                                                            \
        int s0b = (t) * (BK * 2);                                                        \
        const char* gA0 = (const char*)Ap + (size_t)row_me * (S_ * 2) + s0b + kb_me;     \
        const char* gB0 = (const char*)Bp + (size_t)row_me * (S_ * 2) + s0b + kb_me;     \
        char* lA = (char*)(&sA[bufidx][0]) + wave * 1024;                                \
        char* lB = (char*)(&sB[bufidx][0]) + wave * 1024;                                \
        __builtin_amdgcn_global_load_lds((const __attribute__((address_space(1))) void*)gA0,               \
                                         (__attribute__((address_space(3))) void*)lA, 16, 0, 0);           \
        __builtin_amdgcn_global_load_lds((const __attribute__((address_space(1))) void*)(gA0 + 64*(S_*2)), \
                                         (__attribute__((address_space(3))) void*)(lA + 4096), 16, 0, 0);  \
        __builtin_amdgcn_global_load_lds((const __attribute__((address_space(1))) void*)gB0,               \
                                         (__attribute__((address_space(3))) void*)lB, 16, 0, 0);           \
        __builtin_amdgcn_global_load_lds((const __attribute__((address_space(1))) void*)(gB0 + 64*(S_*2)), \
                                         (__attribute__((address_space(3))) void*)(lB + 4096), 16, 0, 0);  \
    } while (0)

    STAGE(0, 0);
    asm volatile("s_waitcnt vmcnt(0)" ::: "memory");
    __syncthreads();

#pragma unroll 2
    for (int t = 0; t < NT; ++t) {
        const int cur = t & 1;
        if (t + 1 < NT) STAGE(cur ^ 1, t + 1);   // prefetch next K-slab

        const __hip_bfloat16* lA = &sA[cur][0];
        const __hip_bfloat16* lB = &sB[cur][0];
        bf16x8 af[4], bfr[4];
#pragma unroll
        for (int mI = 0; mI < 4; ++mI)
            af[mI] = *reinterpret_cast<const bf16x8*>(lA + (wr*64 + mI*16 + lrow) * BK + half * 8);
#pragma unroll
        for (int nI = 0; nI < 4; ++nI)
            bfr[nI] = *reinterpret_cast<const bf16x8*>(lB + (wc*64 + nI*16 + lrow) * BK + half * 8);
#pragma unroll
        for (int mI = 0; mI < 4; ++mI)
#pragma unroll
            for (int nI = 0; nI < 4; ++nI)
                acc[mI][nI] = __builtin_amdgcn_mfma_f32_16x16x32_bf16(af[mI], bfr[nI], acc[mI][nI], 0, 0, 0);

        __syncthreads();   // compiler drains vmcnt+lgkmcnt here (buffers safe to swap)
    }
#undef STAGE

    // C/D layout (verified m89/m91): col = lane&15 (from B), row = (lane>>4)*4 + reg (from A)
    float* Op = outer + (size_t)bc * (I_ * I_);
#pragma unroll
    for (int mI = 0; mI < 4; ++mI) {
        int ii = i0 + wr*64 + mI*16 + half*4;
#pragma unroll
        for (int nI = 0; nI < 4; ++nI) {
            int jj = j0 + wc*64 + nI*16 + lrow;
#pragma unroll
            for (int r = 0; r < 4; ++r)
                Op[(size_t)(ii + r) * I_ + jj] = acc[mI][nI][r];
        }
    }
}

// ---------------------------------------------------------------------------
// Pass 2: out[b,i,j,c] = bo[c] + (1/S) * sum_c' Wo[c,c'] * outer[(b,c'),i,j]
// ---------------------------------------------------------------------------
__global__ __launch_bounds__(256) void wo_kernel(
    const float* __restrict__ outer,
    const float* __restrict__ Wo, const float* __restrict__ bo,
    float* __restrict__ out)
{
    int tid = blockIdx.x * 256 + threadIdx.x;   // ((b*I + i)*J + j)
    int j  = tid & (I_ - 1);
    int bi = tid >> 9;
    int i  = bi & (I_ - 1);
    int b  = bi >> 9;

    const float* ip = outer + ((size_t)(b * C_) * I_ + i) * I_ + j;
    float v[C_];
#pragma unroll
    for (int c = 0; c < C_; ++c) v[c] = ip[(size_t)c * (I_ * I_)] * (1.f / S_);

    float o[C_];
#pragma unroll
    for (int c = 0; c < C_; ++c) {
        float acc = bo[c];
#pragma unroll
        for (int k = 0; k < C_; ++k) acc = fmaf(Wo[c * C_ + k], v[k], acc);
        o[c] = acc;
    }

    float* op = out + (size_t)tid * C_;
#pragma unroll
    for (int vv = 0; vv < 8; ++vv) {
        float4 t4 = { o[4*vv+0], o[4*vv+1], o[4*vv+2], o[4*vv+3] };
        reinterpret_cast<float4*>(op)[vv] = t4;
    }
}

// ---------------------------------------------------------------------------
extern "C" void kernel_launch(void* const* d_in, const int* in_sizes, int n_in,
                              void* d_out, int out_size, void* d_ws, size_t ws_size,
                              hipStream_t stream) {
    const float* m    = (const float*)d_in[0];
    const float* ln_g = (const float*)d_in[1];
    const float* ln_b = (const float*)d_in[2];
    const float* Wa   = (const float*)d_in[3];
    const float* ba   = (const float*)d_in[4];
    const float* Wb   = (const float*)d_in[5];
    const float* bb   = (const float*)d_in[6];
    const float* Wo   = (const float*)d_in[7];
    const float* bo   = (const float*)d_in[8];
    float* out = (float*)d_out;

    const size_t nAB = (size_t)B_ * C_ * I_ * S_;   // 33,554,432 elems (64 MiB bf16 each)
    const size_t nO  = (size_t)B_ * C_ * I_ * I_;   // 16,777,216 elems (64 MiB fp32)
    const size_t need = nAB * 2 * sizeof(__hip_bfloat16) + nO * sizeof(float); // 192 MiB
    if (ws_size < need) return;   // diagnostic: output stays zero -> ws too small

    __hip_bfloat16* a_t = (__hip_bfloat16*)d_ws;
    __hip_bfloat16* b_t = a_t + nAB;
    float* outer = (float*)(b_t + nAB);

    ln_proj_kernel<<<B_ * (I_ / 4) * (S_ / 64), 256, 0, stream>>>(m, ln_g, ln_b, Wa, ba, Wb, bb, a_t, b_t);
    opm_gemm_kernel<<<B_ * C_ * 16, 256, 0, stream>>>(a_t, b_t, outer);
    wo_kernel<<<(B_ * I_ * I_) / 256, 256, 0, stream>>>(outer, Wo, bo, out);
}

// Round 6
// 166.805 us; speedup vs baseline: 2.5012x; 1.0629x over previous
//
#include <hip/hip_runtime.h>
#include <hip/hip_bf16.h>

// Problem constants
#define B_ 2
#define S_ 1024
#define I_ 512
#define C_ 32
#define EPS_ 1e-5f

// GEMM tiling
#define BM 128
#define BN 128
#define BK 32
#define NT (S_ / BK)   // 32 K-steps

typedef __attribute__((ext_vector_type(8))) short bf16x8;   // 8 bf16 = 4 VGPRs (MFMA A/B frag)
typedef __attribute__((ext_vector_type(4))) short bf16x4;   // 4 bf16 = 8 B
typedef __attribute__((ext_vector_type(4))) float f32x4;    // MFMA C/D frag

static __device__ __forceinline__ short f2bf(float f) {
    union { __hip_bfloat16 h; short s; } u;
    u.h = __float2bfloat16(f);
    return u.s;
}

// ---------------------------------------------------------------------------
// Pass 0 (v5): fused stage+LN + MFMA projection, bank-conflict-free.
//
// Round-5 post-mortem: v4's mhf write had i_l only in byte bits >=10 (outside
// the bank field) -> 64 lanes on 4 bank-pairs = 16-way conflict (5.24M
// counted). Fix A: XOR-swizzle byte ^= (pt>>2)<<5 (pt>>2 == i_l, derivable
// from pt on the read side where it's wave-uniform) -> 16 distinct pairs.
// Fix B: occupancy was 4 blocks/CU (34KiB LDS); trb now OVERLAYS mhf with an
// extra barrier after the A-frag reads -> 18KiB total -> 6-8 blocks/CU.
// ---------------------------------------------------------------------------
__global__ __launch_bounds__(256) void ln_proj_kernel(
    const float* __restrict__ m,
    const float* __restrict__ g, const float* __restrict__ beta,
    const float* __restrict__ Wa, const float* __restrict__ ba,
    const float* __restrict__ Wb, const float* __restrict__ bb,
    __hip_bfloat16* __restrict__ a_t, __hip_bfloat16* __restrict__ b_t)
{
    __shared__ __align__(16) __hip_bfloat16 lds[9216];  // 18 KiB, phase-shared:
    // phase A/B: swizzled frag-linear mh (16 KiB); phase C: transpose buf (18 KiB)

    const int tid  = threadIdx.x;
    const int lane = tid & 63;
    const int w    = tid >> 6;
    const int lo   = lane & 15;
    const int hi   = lane >> 4;

    const int blk = blockIdx.x;                 // ((b*(I/4) + ig)*(S/64) + sg)
    const int sg = blk & 15;
    const int ig = (blk >> 4) & 127;
    const int b  = blk >> 11;
    const int s0 = sg * 64;
    const int i0 = ig * 4;

    // ---- B-frags: Wa/Wb rows as bf16x8 (lane l: W[c=(f&1)*16+lo][k=hi*8+e]) ----
    bf16x8 bw[4];
    float biasv[4];
#pragma unroll
    for (int f = 0; f < 4; ++f) {
        const float* Wsrc = (f & 2) ? Wb : Wa;
        const float* bsrc = (f & 2) ? bb : ba;
        int c = (f & 1) * 16 + lo;
        const float* src = Wsrc + c * C_ + hi * 8;
        float4 u0 = *reinterpret_cast<const float4*>(src);
        float4 u1 = *reinterpret_cast<const float4*>(src + 4);
        bf16x8 ch;
        ch[0] = f2bf(u0.x); ch[1] = f2bf(u0.y); ch[2] = f2bf(u0.z); ch[3] = f2bf(u0.w);
        ch[4] = f2bf(u1.x); ch[5] = f2bf(u1.y); ch[6] = f2bf(u1.z); ch[7] = f2bf(u1.w);
        bw[f] = ch;
        biasv[f] = bsrc[c];
    }

    // ---- fused stage + LN; swizzled frag-linear write ----
    const int slot = lane & 7;            // c-range slot*4..slot*4+3
    const int i_l  = (lane >> 3) & 3;
    const float4 gg = *reinterpret_cast<const float4*>(g + slot * 4);
    const float4 gb = *reinterpret_cast<const float4*>(beta + slot * 4);

    const float* mb = m + ((size_t)(b * S_ + s0) * I_ + i0) * C_;
    char* ldsb = reinterpret_cast<char*>(lds);
#pragma unroll
    for (int it = 0; it < 8; ++it) {
        int g4  = it * 256 + tid;
        int s_l = g4 >> 5;                      // 0..63
        float4 v = *reinterpret_cast<const float4*>(
            mb + (size_t)s_l * (I_ * C_) + (i_l * 8 + slot) * 4);

        float s1 = v.x + v.y + v.z + v.w;
        float s2 = v.x*v.x + v.y*v.y + v.z*v.z + v.w*v.w;
#pragma unroll
        for (int d = 1; d < 8; d <<= 1) {
            s1 += __shfl_xor(s1, d, 64);
            s2 += __shfl_xor(s2, d, 64);
        }
        float mu  = s1 * (1.f / C_);
        float var = s2 * (1.f / C_) - mu * mu;
        float rs  = rsqrtf(var + EPS_);

        bf16x4 pk;
        pk[0] = f2bf((v.x - mu) * rs * gg.x + gb.x);
        pk[1] = f2bf((v.y - mu) * rs * gg.y + gb.y);
        pk[2] = f2bf((v.z - mu) * rs * gg.z + gb.z);
        pk[3] = f2bf((v.w - mu) * rs * gg.w + gb.w);

        // frag-linear + XOR swizzle: pos p = i_l*64 + s_l, k0 = slot*4
        int p    = i_l * 64 + s_l;
        int pt   = p >> 4;
        int byte = (pt * 1024 + (slot >> 1) * 256 + (p & 15) * 16 + (slot & 1) * 8)
                   ^ ((pt >> 2) << 5);          // pt>>2 == i_l -> into bank bits 5-6
        *reinterpret_cast<bf16x4*>(ldsb + byte) = pk;
    }
    __syncthreads();

    // ---- A-frag reads (swizzle is wave-uniform here: pt = w*4+q) ----
    bf16x8 af[4];
#pragma unroll
    for (int q = 0; q < 4; ++q) {
        int pt   = w * 4 + q;
        int byte = (pt * 1024 + lane * 16) ^ ((pt >> 2) << 5);
        af[q] = *reinterpret_cast<const bf16x8*>(ldsb + byte);
    }
    __syncthreads();   // all reads done -> trb may overlay mhf

    // ---- 16 MFMA (register-only) ----
    f32x4 d[4][4];
#pragma unroll
    for (int q = 0; q < 4; ++q)
#pragma unroll
        for (int f = 0; f < 4; ++f)
            d[q][f] = __builtin_amdgcn_mfma_f32_16x16x32_bf16(
                af[q], bw[f], (f32x4){0.f, 0.f, 0.f, 0.f}, 0, 0, 0);

    // ---- bias + transpose + store, time-shared per projection (wave-private) ----
    __hip_bfloat16* trw = lds + w * 2304;       // 4 waves x 2304 elems = 18 KiB
#pragma unroll
    for (int p = 0; p < 2; ++p) {
#pragma unroll
        for (int q = 0; q < 4; ++q)
#pragma unroll
            for (int fh = 0; fh < 2; ++fh) {
                int f = p * 2 + fh;
                bf16x4 v4;
#pragma unroll
                for (int r = 0; r < 4; ++r) v4[r] = f2bf(d[q][f][r] + biasv[f]);
                int c = fh * 16 + lo;
                int s = q * 16 + hi * 4;
                *reinterpret_cast<bf16x4*>(trw + c * 72 + s) = v4;
            }
        __hip_bfloat16* outp = p ? b_t : a_t;
#pragma unroll
        for (int cg = 0; cg < 4; ++cg) {
            int c  = cg * 8 + (lane >> 3);
            int s8 = (lane & 7) * 8;
            bf16x8 vv = *reinterpret_cast<const bf16x8*>(trw + c * 72 + s8);
            size_t off = ((size_t)(b * C_ + c) * I_ + (i0 + w)) * S_ + s0 + s8;
            *reinterpret_cast<bf16x8*>(outp + off) = vv;   // 128B/wave contiguous
        }
    }
}

// ---------------------------------------------------------------------------
// Pass 1: 64 independent GEMMs (one per (b,c)): outer[bc][i][j] = sum_s A[i,s]*B[j,s]
// m97-style structure + T1 chunked XCD swizzle. v5: epilogue folds 1/S and
// stores bf16 (halves C-write traffic and pass-2 reads; adds ~3e-5 abs err).
// ---------------------------------------------------------------------------
__global__ __launch_bounds__(256) void opm_gemm_kernel(
    const __hip_bfloat16* __restrict__ a_t,
    const __hip_bfloat16* __restrict__ b_t,
    __hip_bfloat16* __restrict__ outer)
{
    __shared__ __align__(16) __hip_bfloat16 sA[2][BM * BK];  // 8 KiB per buf
    __shared__ __align__(16) __hip_bfloat16 sB[2][BN * BK];

    const int tid  = threadIdx.x;
    const int wave = tid >> 6;
    const int lane = tid & 63;
    // T1: grid = 1024 (divisible by 8 XCDs) -> bijective chunked swizzle
    const int swz  = (blockIdx.x & 7) * 128 + (blockIdx.x >> 3);
    const int bc   = swz >> 4;            // (b*C + c), 0..63
    const int tile = swz & 15;            // 4x4 output tiles per GEMM
    const int i0   = (tile >> 2) * BM;
    const int j0   = (tile & 3)  * BN;

    const __hip_bfloat16* Ap = a_t + ((size_t)bc * I_ + i0) * S_;
    const __hip_bfloat16* Bp = b_t + ((size_t)bc * I_ + j0) * S_;

    f32x4 acc[4][4];
#pragma unroll
    for (int mI = 0; mI < 4; ++mI)
#pragma unroll
        for (int nI = 0; nI < 4; ++nI)
            acc[mI][nI] = (f32x4){0.f, 0.f, 0.f, 0.f};

    const int wr = wave >> 1;      // wave row (0..1)
    const int wc = wave & 1;       // wave col (0..1)
    const int half = lane >> 4;    // k-group 0..3 (k = half*8 + e)
    const int lrow = lane & 15;    // row within 16x16 frag

    const int row_me = tid >> 2;
    const int kb_me  = (tid & 3) * 16;

#define STAGE(bufidx, t) do {                                                            \
        int s0b = (t) * (BK * 2);                                                        \
        const char* gA0 = (const char*)Ap + (size_t)row_me * (S_ * 2) + s0b + kb_me;     \
        const char* gB0 = (const char*)Bp + (size_t)row_me * (S_ * 2) + s0b + kb_me;     \
        char* lA = (char*)(&sA[bufidx][0]) + wave * 1024;                                \
        char* lB = (char*)(&sB[bufidx][0]) + wave * 1024;                                \
        __builtin_amdgcn_global_load_lds((const __attribute__((address_space(1))) void*)gA0,               \
                                         (__attribute__((address_space(3))) void*)lA, 16, 0, 0);           \
        __builtin_amdgcn_global_load_lds((const __attribute__((address_space(1))) void*)(gA0 + 64*(S_*2)), \
                                         (__attribute__((address_space(3))) void*)(lA + 4096), 16, 0, 0);  \
        __builtin_amdgcn_global_load_lds((const __attribute__((address_space(1))) void*)gB0,               \
                                         (__attribute__((address_space(3))) void*)lB, 16, 0, 0);           \
        __builtin_amdgcn_global_load_lds((const __attribute__((address_space(1))) void*)(gB0 + 64*(S_*2)), \
                                         (__attribute__((address_space(3))) void*)(lB + 4096), 16, 0, 0);  \
    } while (0)

    STAGE(0, 0);
    asm volatile("s_waitcnt vmcnt(0)" ::: "memory");
    __syncthreads();

#pragma unroll 2
    for (int t = 0; t < NT; ++t) {
        const int cur = t & 1;
        if (t + 1 < NT) STAGE(cur ^ 1, t + 1);   // prefetch next K-slab

        const __hip_bfloat16* lA = &sA[cur][0];
        const __hip_bfloat16* lB = &sB[cur][0];
        bf16x8 af[4], bfr[4];
#pragma unroll
        for (int mI = 0; mI < 4; ++mI)
            af[mI] = *reinterpret_cast<const bf16x8*>(lA + (wr*64 + mI*16 + lrow) * BK + half * 8);
#pragma unroll
        for (int nI = 0; nI < 4; ++nI)
            bfr[nI] = *reinterpret_cast<const bf16x8*>(lB + (wc*64 + nI*16 + lrow) * BK + half * 8);
#pragma unroll
        for (int mI = 0; mI < 4; ++mI)
#pragma unroll
            for (int nI = 0; nI < 4; ++nI)
                acc[mI][nI] = __builtin_amdgcn_mfma_f32_16x16x32_bf16(af[mI], bfr[nI], acc[mI][nI], 0, 0, 0);

        __syncthreads();   // compiler drains vmcnt+lgkmcnt here (buffers safe to swap)
    }
#undef STAGE

    // C/D layout (verified m89/m91): col = lane&15 (from B), row = (lane>>4)*4 + reg (from A)
    __hip_bfloat16* Op = outer + (size_t)bc * (I_ * I_);
#pragma unroll
    for (int mI = 0; mI < 4; ++mI) {
        int ii = i0 + wr*64 + mI*16 + half*4;
#pragma unroll
        for (int nI = 0; nI < 4; ++nI) {
            int jj = j0 + wc*64 + nI*16 + lrow;
#pragma unroll
            for (int r = 0; r < 4; ++r)
                Op[(size_t)(ii + r) * I_ + jj] =
                    __float2bfloat16(acc[mI][nI][r] * (1.f / S_));
        }
    }
}

// ---------------------------------------------------------------------------
// Pass 2: out[b,i,j,c] = bo[c] + sum_c' Wo[c,c'] * outer_scaled[(b,c'),i,j]
// outer is bf16 with 1/S pre-folded. Per-c' loads: 64 lanes x 2B consecutive
// = 128B segments; 32 fp32 outputs per thread -> 8x float4 stores.
// ---------------------------------------------------------------------------
__global__ __launch_bounds__(256) void wo_kernel(
    const __hip_bfloat16* __restrict__ outer,
    const float* __restrict__ Wo, const float* __restrict__ bo,
    float* __restrict__ out)
{
    int tid = blockIdx.x * 256 + threadIdx.x;   // ((b*I + i)*J + j)
    int j  = tid & (I_ - 1);
    int bi = tid >> 9;
    int i  = bi & (I_ - 1);
    int b  = bi >> 9;

    const __hip_bfloat16* ip = outer + ((size_t)(b * C_) * I_ + i) * I_ + j;
    float v[C_];
#pragma unroll
    for (int c = 0; c < C_; ++c) v[c] = __bfloat162float(ip[(size_t)c * (I_ * I_)]);

    float o[C_];
#pragma unroll
    for (int c = 0; c < C_; ++c) {
        float acc = bo[c];
#pragma unroll
        for (int k = 0; k < C_; ++k) acc = fmaf(Wo[c * C_ + k], v[k], acc);
        o[c] = acc;
    }

    float* op = out + (size_t)tid * C_;
#pragma unroll
    for (int vv = 0; vv < 8; ++vv) {
        float4 t4 = { o[4*vv+0], o[4*vv+1], o[4*vv+2], o[4*vv+3] };
        reinterpret_cast<float4*>(op)[vv] = t4;
    }
}

// ---------------------------------------------------------------------------
extern "C" void kernel_launch(void* const* d_in, const int* in_sizes, int n_in,
                              void* d_out, int out_size, void* d_ws, size_t ws_size,
                              hipStream_t stream) {
    const float* m    = (const float*)d_in[0];
    const float* ln_g = (const float*)d_in[1];
    const float* ln_b = (const float*)d_in[2];
    const float* Wa   = (const float*)d_in[3];
    const float* ba   = (const float*)d_in[4];
    const float* Wb   = (const float*)d_in[5];
    const float* bb   = (const float*)d_in[6];
    const float* Wo   = (const float*)d_in[7];
    const float* bo   = (const float*)d_in[8];
    float* out = (float*)d_out;

    const size_t nAB = (size_t)B_ * C_ * I_ * S_;   // 33,554,432 elems (64 MiB bf16 each)
    const size_t nO  = (size_t)B_ * C_ * I_ * I_;   // 16,777,216 elems (32 MiB bf16)
    const size_t need = (nAB * 2 + nO) * sizeof(__hip_bfloat16);  // 160 MiB
    if (ws_size < need) return;   // diagnostic: output stays zero -> ws too small

    __hip_bfloat16* a_t = (__hip_bfloat16*)d_ws;
    __hip_bfloat16* b_t = a_t + nAB;
    __hip_bfloat16* outer = b_t + nAB;

    ln_proj_kernel<<<B_ * (I_ / 4) * (S_ / 64), 256, 0, stream>>>(m, ln_g, ln_b, Wa, ba, Wb, bb, a_t, b_t);
    opm_gemm_kernel<<<B_ * C_ * 16, 256, 0, stream>>>(a_t, b_t, outer);
    wo_kernel<<<(B_ * I_ * I_) / 256, 256, 0, stream>>>(outer, Wo, bo, out);
}

// Round 7
// 145.567 us; speedup vs baseline: 2.8661x; 1.1459x over previous
//
#include <hip/hip_runtime.h>
#include <hip/hip_bf16.h>

// Problem constants
#define B_ 2
#define S_ 1024
#define I_ 512
#define C_ 32
#define EPS_ 1e-5f

// Padded plane stride for a_t/b_t: 1 MiB + 8 KiB (breaks power-of-2 channel
// and L2-set aliasing of the c-plane-strided wave stores in ln_proj).
#define PLST (I_ * S_ + 4096)

// GEMM tiling: 256x256 tile, 8 waves, BK=32, double-buffered.
#define GBM 256
#define GBN 256
#define BK 32
#define NT (S_ / BK)   // 32 K-steps

typedef __attribute__((ext_vector_type(8))) short bf16x8;   // 8 bf16 = 4 VGPRs (MFMA A/B frag)
typedef __attribute__((ext_vector_type(4))) short bf16x4;   // 4 bf16 = 8 B
typedef __attribute__((ext_vector_type(4))) float f32x4;    // MFMA C/D frag

static __device__ __forceinline__ short f2bf(float f) {
    union { __hip_bfloat16 h; short s; } u;
    u.h = __float2bfloat16(f);
    return u.s;
}

// ---------------------------------------------------------------------------
// Pass 0 (v7): per-thread-row LN (zero cross-lane ops) + MFMA projection.
//
// Round-6 post-mortem: occupancy stuck at 26% independent of LDS size; VALU
// 18%, HBM 27%, conflicts small -> latency-bound. Suspect: 48 ds_swizzle
// (__shfl_xor) per thread in 3-deep dependent chains inside the stage loop.
// v7: thread <-> one full (i,s) row (128B contiguous). 8x float4 loads hit
// dense 512B windows (L1-reused across the unroll); LN is pure register
// math; pack bf16 and ds_write_b128 x4 directly in MFMA-frag order with
// XOR swizzle (bank-quad balanced at volume floor, wave-uniform for reader).
// Then: 4x ds_read_b128 A-frags, 16 MFMA vs in-reg Wa/Wb B-frags, transpose
// through per-wave padded buffer, 128B-coalesced stores at PADDED plane
// stride. LDS 18 KiB, no shuffles, 2 barriers.
// ---------------------------------------------------------------------------
__global__ __launch_bounds__(256) void ln_proj_kernel(
    const float* __restrict__ m,
    const float* __restrict__ g, const float* __restrict__ beta,
    const float* __restrict__ Wa, const float* __restrict__ ba,
    const float* __restrict__ Wb, const float* __restrict__ bb,
    __hip_bfloat16* __restrict__ a_t, __hip_bfloat16* __restrict__ b_t)
{
    __shared__ __align__(16) __hip_bfloat16 lds[9216];  // 18 KiB, phase-shared

    const int tid  = threadIdx.x;
    const int lane = tid & 63;
    const int w    = tid >> 6;
    const int lo   = lane & 15;
    const int hi   = lane >> 4;

    const int blk = blockIdx.x;                 // ((b*(I/4) + ig)*(S/64) + sg)
    const int sg = blk & 15;
    const int ig = (blk >> 4) & 127;
    const int b  = blk >> 11;
    const int s0 = sg * 64;
    const int i0 = ig * 4;

    // thread <-> row: i_l = tid&3, s_l = tid>>2 (memory-consecutive rows)
    const int i_l = tid & 3;
    const int s_l = tid >> 2;        // 0..63 ; within wave w: s_l in [16w,16w+16)

    // ---- B-frags: Wa/Wb rows as bf16x8 (lane l: W[c=(f&1)*16+lo][k=hi*8+e]) ----
    bf16x8 bw[4];
    float biasv[4];
#pragma unroll
    for (int f = 0; f < 4; ++f) {
        const float* Wsrc = (f & 2) ? Wb : Wa;
        const float* bsrc = (f & 2) ? bb : ba;
        int c = (f & 1) * 16 + lo;
        const float* src = Wsrc + c * C_ + hi * 8;
        float4 u0 = *reinterpret_cast<const float4*>(src);
        float4 u1 = *reinterpret_cast<const float4*>(src + 4);
        bf16x8 ch;
        ch[0] = f2bf(u0.x); ch[1] = f2bf(u0.y); ch[2] = f2bf(u0.z); ch[3] = f2bf(u0.w);
        ch[4] = f2bf(u1.x); ch[5] = f2bf(u1.y); ch[6] = f2bf(u1.z); ch[7] = f2bf(u1.w);
        bw[f] = ch;
        biasv[f] = bsrc[c];
    }

    // ---- load own row (8 independent float4, dense 512B windows per wave) ----
    const float* mp = m + ((size_t)(b * S_ + s0 + s_l) * I_ + i0 + i_l) * C_;
    float x[C_];
#pragma unroll
    for (int v = 0; v < 8; ++v) {
        float4 t = reinterpret_cast<const float4*>(mp)[v];
        x[4*v+0] = t.x; x[4*v+1] = t.y; x[4*v+2] = t.z; x[4*v+3] = t.w;
    }

    // ---- LN, pure register math ----
    float mu = 0.f;
#pragma unroll
    for (int c = 0; c < C_; ++c) mu += x[c];
    mu *= (1.f / C_);
    float var = 0.f;
#pragma unroll
    for (int c = 0; c < C_; ++c) { float dd = x[c] - mu; var += dd * dd; }
    float rs = rsqrtf(var * (1.f / C_) + EPS_);
#pragma unroll
    for (int c = 0; c < C_; ++c) x[c] = (x[c] - mu) * rs * g[c] + beta[c];

    // ---- pack + swizzled frag-linear LDS write ----
    // pos p = i_l*64 + s_l; pt = p>>4 = i_l*4 + (s_l>>4); elem = pt*512 +
    // ks*128 + (p&15)*8. XOR byte bits 5-6 by i_l (== pt>>2): bank-quad
    // balance 8 lanes/quad (floor); reader sees wave-uniform XOR.
    char* ldsb = reinterpret_cast<char*>(lds);
    {
        const int pt   = i_l * 4 + (s_l >> 4);
        const int base = pt * 1024 + (s_l & 15) * 16;
        const int swzb = (i_l & 3) << 5;
#pragma unroll
        for (int ks = 0; ks < 4; ++ks) {
            bf16x8 ch;
#pragma unroll
            for (int e = 0; e < 8; ++e) ch[e] = f2bf(x[ks * 8 + e]);
            *reinterpret_cast<bf16x8*>(ldsb + ((base + ks * 256) ^ swzb)) = ch;
        }
    }
    __syncthreads();

    // ---- A-frag reads (XOR is wave-uniform: pt = w*4+q -> pt>>2 = w) ----
    bf16x8 af[4];
#pragma unroll
    for (int q = 0; q < 4; ++q) {
        int pt   = w * 4 + q;
        int byte = (pt * 1024 + lane * 16) ^ ((pt >> 2) << 5);
        af[q] = *reinterpret_cast<const bf16x8*>(ldsb + byte);
    }
    __syncthreads();   // all frag reads done -> transpose buf may overlay

    // ---- 16 MFMA (register-only) ----
    f32x4 d[4][4];
#pragma unroll
    for (int q = 0; q < 4; ++q)
#pragma unroll
        for (int f = 0; f < 4; ++f)
            d[q][f] = __builtin_amdgcn_mfma_f32_16x16x32_bf16(
                af[q], bw[f], (f32x4){0.f, 0.f, 0.f, 0.f}, 0, 0, 0);

    // ---- bias + transpose + store, time-shared per projection ----
    __hip_bfloat16* trw = lds + w * 2304;       // 4 waves x 2304 elems = 18 KiB
#pragma unroll
    for (int p = 0; p < 2; ++p) {
#pragma unroll
        for (int q = 0; q < 4; ++q)
#pragma unroll
            for (int fh = 0; fh < 2; ++fh) {
                int f = p * 2 + fh;
                bf16x4 v4;
#pragma unroll
                for (int r = 0; r < 4; ++r) v4[r] = f2bf(d[q][f][r] + biasv[f]);
                int c = fh * 16 + lo;
                int s = q * 16 + hi * 4;
                *reinterpret_cast<bf16x4*>(trw + c * 72 + s) = v4;
            }
        __hip_bfloat16* outp = p ? b_t : a_t;
#pragma unroll
        for (int cg = 0; cg < 4; ++cg) {
            int c  = cg * 8 + (lane >> 3);
            int s8 = (lane & 7) * 8;
            bf16x8 vv = *reinterpret_cast<const bf16x8*>(trw + c * 72 + s8);
            size_t off = (size_t)(b * C_ + c) * PLST + (size_t)(i0 + w) * S_ + s0 + s8;
            *reinterpret_cast<bf16x8*>(outp + off) = vv;   // 128B/wave contiguous
        }
    }
}

// ---------------------------------------------------------------------------
// Pass 1 (v7): 64 independent GEMMs, 256x256 tiles (halves staged traffic
// 512->256 MB), 8 waves, BK=32 double-buffered via global_load_lds w=16.
// LDS read-side XOR swizzle (byte ^= ((row>>1)&3)<<4) kills the 8-way
// ds_read_b128 conflict; inverse XOR pre-applied to the GLOBAL source
// address (rule #21: gload_lds dest must stay linear). T1 chunked XCD
// swizzle; epilogue folds 1/S, stores bf16.
// ---------------------------------------------------------------------------
__global__ __launch_bounds__(512, 2) void opm_gemm_kernel(
    const __hip_bfloat16* __restrict__ a_t,
    const __hip_bfloat16* __restrict__ b_t,
    __hip_bfloat16* __restrict__ outer)
{
    __shared__ __align__(16) __hip_bfloat16 sA[2][GBM * BK];  // 16 KiB per buf
    __shared__ __align__(16) __hip_bfloat16 sB[2][GBN * BK];  // total 64 KiB

    const int tid  = threadIdx.x;
    const int wave = tid >> 6;           // 0..7
    const int lane = tid & 63;
    // T1: 256 blocks % 8 == 0 -> bijective chunked swizzle (32 blocks/XCD)
    const int swz  = (blockIdx.x & 7) * 32 + (blockIdx.x >> 3);
    const int bc   = swz >> 2;           // (b*C + c), 0..63
    const int tile = swz & 3;            // 2x2 output tiles per GEMM
    const int i0   = (tile >> 1) * GBM;
    const int j0   = (tile & 1)  * GBN;

    const __hip_bfloat16* Ap = a_t + (size_t)bc * PLST + (size_t)i0 * S_;
    const __hip_bfloat16* Bp = b_t + (size_t)bc * PLST + (size_t)j0 * S_;

    f32x4 acc[8][4];
#pragma unroll
    for (int mI = 0; mI < 8; ++mI)
#pragma unroll
        for (int nI = 0; nI < 4; ++nI)
            acc[mI][nI] = (f32x4){0.f, 0.f, 0.f, 0.f};

    const int wr = wave >> 2;      // wave row (0..1): rows [wr*128, +128)
    const int wc = wave & 3;       // wave col (0..3): cols [wc*64, +64)
    const int half = lane >> 4;    // k-group
    const int lrow = lane & 15;

    // staging: slot q = r*512 + tid; row = q>>2 = r*128 + (tid>>2); chunk q&3.
    // source pre-swizzle: kb = ((q&3) ^ ((row>>1)&3))*16  (same for r=0,1
    // since 128 is a multiple of 4 in row>>1 terms). LDS dest stays linear.
    const int row_me = tid >> 2;                       // 0..127
    const int kb_me  = (((tid & 3) ^ ((row_me >> 1) & 3)) << 4);

#define STAGE(bufidx, t) do {                                                              \
        int s0b = (t) * (BK * 2);                                                          \
        const char* gA0 = (const char*)Ap + (size_t)row_me * (S_ * 2) + s0b + kb_me;       \
        const char* gB0 = (const char*)Bp + (size_t)row_me * (S_ * 2) + s0b + kb_me;       \
        char* lA = (char*)(&sA[bufidx][0]) + tid * 16;                                     \
        char* lB = (char*)(&sB[bufidx][0]) + tid * 16;                                     \
        __builtin_amdgcn_global_load_lds((const __attribute__((address_space(1))) void*)gA0,                \
                                         (__attribute__((address_space(3))) void*)lA, 16, 0, 0);            \
        __builtin_amdgcn_global_load_lds((const __attribute__((address_space(1))) void*)(gA0 + 128*(S_*2)), \
                                         (__attribute__((address_space(3))) void*)(lA + 8192), 16, 0, 0);   \
        __builtin_amdgcn_global_load_lds((const __attribute__((address_space(1))) void*)gB0,                \
                                         (__attribute__((address_space(3))) void*)lB, 16, 0, 0);            \
        __builtin_amdgcn_global_load_lds((const __attribute__((address_space(1))) void*)(gB0 + 128*(S_*2)), \
                                         (__attribute__((address_space(3))) void*)(lB + 8192), 16, 0, 0);   \
    } while (0)

    STAGE(0, 0);
    asm volatile("s_waitcnt vmcnt(0)" ::: "memory");
    __syncthreads();

#pragma unroll 2
    for (int t = 0; t < NT; ++t) {
        const int cur = t & 1;
        if (t + 1 < NT) STAGE(cur ^ 1, t + 1);   // prefetch next K-slab

        const char* lA = (const char*)(&sA[cur][0]);
        const char* lB = (const char*)(&sB[cur][0]);
        bf16x8 af[8], bfr[4];
#pragma unroll
        for (int mI = 0; mI < 8; ++mI) {
            int row  = wr * 128 + mI * 16 + lrow;
            int byte = (row * 64 + half * 16) ^ (((row >> 1) & 3) << 4);
            af[mI] = *reinterpret_cast<const bf16x8*>(lA + byte);
        }
#pragma unroll
        for (int nI = 0; nI < 4; ++nI) {
            int row  = wc * 64 + nI * 16 + lrow;
            int byte = (row * 64 + half * 16) ^ (((row >> 1) & 3) << 4);
            bfr[nI] = *reinterpret_cast<const bf16x8*>(lB + byte);
        }
#pragma unroll
        for (int mI = 0; mI < 8; ++mI)
#pragma unroll
            for (int nI = 0; nI < 4; ++nI)
                acc[mI][nI] = __builtin_amdgcn_mfma_f32_16x16x32_bf16(af[mI], bfr[nI], acc[mI][nI], 0, 0, 0);

        __syncthreads();   // drains vmcnt+lgkmcnt (buffers safe to swap)
    }
#undef STAGE

    // C/D layout: col = lane&15 (from B), row = (lane>>4)*4 + reg (from A)
    __hip_bfloat16* Op = outer + (size_t)bc * (I_ * I_);
#pragma unroll
    for (int mI = 0; mI < 8; ++mI) {
        int ii = i0 + wr * 128 + mI * 16 + half * 4;
#pragma unroll
        for (int nI = 0; nI < 4; ++nI) {
            int jj = j0 + wc * 64 + nI * 16 + lrow;
#pragma unroll
            for (int r = 0; r < 4; ++r)
                Op[(size_t)(ii + r) * I_ + jj] =
                    __float2bfloat16(acc[mI][nI][r] * (1.f / S_));
        }
    }
}

// ---------------------------------------------------------------------------
// Pass 2: out[b,i,j,c] = bo[c] + sum_c' Wo[c,c'] * outer_scaled[(b,c'),i,j]
// outer is bf16 with 1/S pre-folded (L2/L3-resident from pass 1).
// ---------------------------------------------------------------------------
__global__ __launch_bounds__(256) void wo_kernel(
    const __hip_bfloat16* __restrict__ outer,
    const float* __restrict__ Wo, const float* __restrict__ bo,
    float* __restrict__ out)
{
    int tid = blockIdx.x * 256 + threadIdx.x;   // ((b*I + i)*J + j)
    int j  = tid & (I_ - 1);
    int bi = tid >> 9;
    int i  = bi & (I_ - 1);
    int b  = bi >> 9;

    const __hip_bfloat16* ip = outer + ((size_t)(b * C_) * I_ + i) * I_ + j;
    float v[C_];
#pragma unroll
    for (int c = 0; c < C_; ++c) v[c] = __bfloat162float(ip[(size_t)c * (I_ * I_)]);

    float o[C_];
#pragma unroll
    for (int c = 0; c < C_; ++c) {
        float acc = bo[c];
#pragma unroll
        for (int k = 0; k < C_; ++k) acc = fmaf(Wo[c * C_ + k], v[k], acc);
        o[c] = acc;
    }

    float* op = out + (size_t)tid * C_;
#pragma unroll
    for (int vv = 0; vv < 8; ++vv) {
        float4 t4 = { o[4*vv+0], o[4*vv+1], o[4*vv+2], o[4*vv+3] };
        reinterpret_cast<float4*>(op)[vv] = t4;
    }
}

// ---------------------------------------------------------------------------
extern "C" void kernel_launch(void* const* d_in, const int* in_sizes, int n_in,
                              void* d_out, int out_size, void* d_ws, size_t ws_size,
                              hipStream_t stream) {
    const float* m    = (const float*)d_in[0];
    const float* ln_g = (const float*)d_in[1];
    const float* ln_b = (const float*)d_in[2];
    const float* Wa   = (const float*)d_in[3];
    const float* ba   = (const float*)d_in[4];
    const float* Wb   = (const float*)d_in[5];
    const float* bb   = (const float*)d_in[6];
    const float* Wo   = (const float*)d_in[7];
    const float* bo   = (const float*)d_in[8];
    float* out = (float*)d_out;

    const size_t nAB = (size_t)B_ * C_ * PLST;      // padded planes
    const size_t nO  = (size_t)B_ * C_ * I_ * I_;   // 16,777,216 elems (32 MiB bf16)
    const size_t need = (nAB * 2 + nO) * sizeof(__hip_bfloat16);  // ~169 MB
    if (ws_size < need) return;   // diagnostic: output stays zero -> ws too small

    __hip_bfloat16* a_t = (__hip_bfloat16*)d_ws;
    __hip_bfloat16* b_t = a_t + nAB;
    __hip_bfloat16* outer = b_t + nAB;

    ln_proj_kernel<<<B_ * (I_ / 4) * (S_ / 64), 256, 0, stream>>>(m, ln_g, ln_b, Wa, ba, Wb, bb, a_t, b_t);
    opm_gemm_kernel<<<B_ * C_ * 4, 512, 0, stream>>>(a_t, b_t, outer);
    wo_kernel<<<(B_ * I_ * I_) / 256, 256, 0, stream>>>(outer, Wo, bo, out);
}

// Round 8
// 145.415 us; speedup vs baseline: 2.8691x; 1.0010x over previous
//
#include <hip/hip_runtime.h>
#include <hip/hip_bf16.h>

// Problem constants
#define B_ 2
#define S_ 1024
#define I_ 512
#define C_ 32
#define EPS_ 1e-5f

// Padded plane stride for a_t/b_t: 1 MiB + 8 KiB + 128 B (breaks power-of-2
// channel/L2-set aliasing of the c-plane-strided wave stores; +128B adds
// bank diversity across consecutive planes).
#define PLST (I_ * S_ + 4096 + 64)

// GEMM tiling: 256x256 tile, 8 waves, BK=32, double-buffered.
#define GBM 256
#define GBN 256
#define BK 32
#define NT (S_ / BK)   // 32 K-steps

typedef __attribute__((ext_vector_type(8))) short bf16x8;   // 8 bf16 = 4 VGPRs (MFMA A/B frag)
typedef __attribute__((ext_vector_type(4))) short bf16x4;   // 4 bf16 = 8 B
typedef __attribute__((ext_vector_type(4))) float f32x4;    // MFMA C/D frag

static __device__ __forceinline__ short f2bf(float f) {
    union { __hip_bfloat16 h; short s; } u;
    u.h = __float2bfloat16(f);
    return u.s;
}

// ---------------------------------------------------------------------------
// Pass 0 (v8): per-thread-row LN + MFMA projection, ACC-DIET edition.
//
// Round-7 post-mortem: v5/v6/v7 all ~85-93us with nothing saturated ->
// latency-bound. Cause: VGPR_Count 76 EXCLUDES the 64 AGPRs of d[4][4]
// (16 f32x4 live at once) -> ~140 regs/wave -> 3 waves/SIMD cap (occ 23%).
// v8: (a) MFMA restructured as p-loop x q-loop with 2 MFMAs live at a time
// (8 AGPR, ds_writes interleaved); (b) trb no longer overlays mhf (34 KiB
// total, 4 blocks/CU) -> SECOND BARRIER DELETED; (c) m-loads issued before
// weight loads. Target: 4+ waves/SIMD, occupancy 35-45%.
// ---------------------------------------------------------------------------
__global__ __launch_bounds__(256) void ln_proj_kernel(
    const float* __restrict__ m,
    const float* __restrict__ g, const float* __restrict__ beta,
    const float* __restrict__ Wa, const float* __restrict__ ba,
    const float* __restrict__ Wb, const float* __restrict__ bb,
    __hip_bfloat16* __restrict__ a_t, __hip_bfloat16* __restrict__ b_t)
{
    __shared__ __align__(16) __hip_bfloat16 mhf[8192];      // 16 KiB frag-linear mh
    __shared__ __align__(16) __hip_bfloat16 trb[4 * 2304];  // 18 KiB transpose (wave-private slices)

    const int tid  = threadIdx.x;
    const int lane = tid & 63;
    const int w    = tid >> 6;
    const int lo   = lane & 15;
    const int hi   = lane >> 4;

    const int blk = blockIdx.x;                 // ((b*(I/4) + ig)*(S/64) + sg)
    const int sg = blk & 15;
    const int ig = (blk >> 4) & 127;
    const int b  = blk >> 11;
    const int s0 = sg * 64;
    const int i0 = ig * 4;

    // thread <-> row: i_l = tid&3, s_l = tid>>2
    const int i_l = tid & 3;
    const int s_l = tid >> 2;

    // ---- issue own-row loads FIRST (8 independent float4) ----
    const float* mp = m + ((size_t)(b * S_ + s0 + s_l) * I_ + i0 + i_l) * C_;
    float4 mv[8];
#pragma unroll
    for (int v = 0; v < 8; ++v) mv[v] = reinterpret_cast<const float4*>(mp)[v];

    // ---- B-frags: Wa/Wb rows as bf16x8 (latency hidden under m-loads) ----
    bf16x8 bw[4];
    float biasv[4];
#pragma unroll
    for (int f = 0; f < 4; ++f) {
        const float* Wsrc = (f & 2) ? Wb : Wa;
        const float* bsrc = (f & 2) ? bb : ba;
        int c = (f & 1) * 16 + lo;
        const float* src = Wsrc + c * C_ + hi * 8;
        float4 u0 = *reinterpret_cast<const float4*>(src);
        float4 u1 = *reinterpret_cast<const float4*>(src + 4);
        bf16x8 ch;
        ch[0] = f2bf(u0.x); ch[1] = f2bf(u0.y); ch[2] = f2bf(u0.z); ch[3] = f2bf(u0.w);
        ch[4] = f2bf(u1.x); ch[5] = f2bf(u1.y); ch[6] = f2bf(u1.z); ch[7] = f2bf(u1.w);
        bw[f] = ch;
        biasv[f] = bsrc[c];
    }

    // ---- LN, pure register math ----
    float x[C_];
#pragma unroll
    for (int v = 0; v < 8; ++v) {
        x[4*v+0] = mv[v].x; x[4*v+1] = mv[v].y; x[4*v+2] = mv[v].z; x[4*v+3] = mv[v].w;
    }
    float mu = 0.f;
#pragma unroll
    for (int c = 0; c < C_; ++c) mu += x[c];
    mu *= (1.f / C_);
    float var = 0.f;
#pragma unroll
    for (int c = 0; c < C_; ++c) { float dd = x[c] - mu; var += dd * dd; }
    float rs = rsqrtf(var * (1.f / C_) + EPS_);
#pragma unroll
    for (int c = 0; c < C_; ++c) x[c] = (x[c] - mu) * rs * g[c] + beta[c];

    // ---- pack + swizzled frag-linear LDS write ----
    // pos p = i_l*64 + s_l; pt = i_l*4 + (s_l>>4); byte = pt*1024 + ks*256 +
    // (p&15)*16, XOR'd by i_l<<5 (bank-quad balance; wave-uniform on read).
    char* ldsb = reinterpret_cast<char*>(mhf);
    {
        const int pt   = i_l * 4 + (s_l >> 4);
        const int base = pt * 1024 + (s_l & 15) * 16;
        const int swzb = (i_l & 3) << 5;
#pragma unroll
        for (int ks = 0; ks < 4; ++ks) {
            bf16x8 ch;
#pragma unroll
            for (int e = 0; e < 8; ++e) ch[e] = f2bf(x[ks * 8 + e]);
            *reinterpret_cast<bf16x8*>(ldsb + ((base + ks * 256) ^ swzb)) = ch;
        }
    }
    __syncthreads();   // the ONLY barrier

    // ---- A-frag reads once (XOR wave-uniform: pt = w*4+q -> pt>>2 = w) ----
    bf16x8 af[4];
#pragma unroll
    for (int q = 0; q < 4; ++q) {
        int pt   = w * 4 + q;
        int byte = (pt * 1024 + lane * 16) ^ ((pt >> 2) << 5);
        af[q] = *reinterpret_cast<const bf16x8*>(ldsb + byte);
    }

    // ---- p-loop: 2 MFMAs live at a time (8 AGPR), immediate transpose+store ----
    __hip_bfloat16* trw = trb + w * 2304;       // wave-private, no barriers needed
#pragma unroll
    for (int p = 0; p < 2; ++p) {
#pragma unroll
        for (int q = 0; q < 4; ++q) {
#pragma unroll
            for (int fh = 0; fh < 2; ++fh) {
                int f = p * 2 + fh;
                f32x4 d = __builtin_amdgcn_mfma_f32_16x16x32_bf16(
                    af[q], bw[f], (f32x4){0.f, 0.f, 0.f, 0.f}, 0, 0, 0);
                bf16x4 v4;
#pragma unroll
                for (int r = 0; r < 4; ++r) v4[r] = f2bf(d[r] + biasv[f]);
                int c = fh * 16 + lo;
                int s = q * 16 + hi * 4;
                *reinterpret_cast<bf16x4*>(trw + c * 72 + s) = v4;
            }
        }
        __hip_bfloat16* outp = p ? b_t : a_t;
#pragma unroll
        for (int cg = 0; cg < 4; ++cg) {
            int c  = cg * 8 + (lane >> 3);
            int s8 = (lane & 7) * 8;
            bf16x8 vv = *reinterpret_cast<const bf16x8*>(trw + c * 72 + s8);
            size_t off = (size_t)(b * C_ + c) * PLST + (size_t)(i0 + w) * S_ + s0 + s8;
            *reinterpret_cast<bf16x8*>(outp + off) = vv;   // 128B/wave contiguous
        }
    }
}

// ---------------------------------------------------------------------------
// Pass 1 (v7, unchanged): 64 independent GEMMs, 256x256 tiles, 8 waves,
// BK=32 double-buffered via global_load_lds w=16. Read-side XOR swizzle with
// inverse pre-applied to the GLOBAL source (rule #21). T1 chunked XCD
// swizzle; epilogue folds 1/S, stores bf16.
// ---------------------------------------------------------------------------
__global__ __launch_bounds__(512, 2) void opm_gemm_kernel(
    const __hip_bfloat16* __restrict__ a_t,
    const __hip_bfloat16* __restrict__ b_t,
    __hip_bfloat16* __restrict__ outer)
{
    __shared__ __align__(16) __hip_bfloat16 sA[2][GBM * BK];  // 16 KiB per buf
    __shared__ __align__(16) __hip_bfloat16 sB[2][GBN * BK];  // total 64 KiB

    const int tid  = threadIdx.x;
    const int wave = tid >> 6;           // 0..7
    const int lane = tid & 63;
    // T1: 256 blocks % 8 == 0 -> bijective chunked swizzle (32 blocks/XCD)
    const int swz  = (blockIdx.x & 7) * 32 + (blockIdx.x >> 3);
    const int bc   = swz >> 2;           // (b*C + c), 0..63
    const int tile = swz & 3;            // 2x2 output tiles per GEMM
    const int i0   = (tile >> 1) * GBM;
    const int j0   = (tile & 1)  * GBN;

    const __hip_bfloat16* Ap = a_t + (size_t)bc * PLST + (size_t)i0 * S_;
    const __hip_bfloat16* Bp = b_t + (size_t)bc * PLST + (size_t)j0 * S_;

    f32x4 acc[8][4];
#pragma unroll
    for (int mI = 0; mI < 8; ++mI)
#pragma unroll
        for (int nI = 0; nI < 4; ++nI)
            acc[mI][nI] = (f32x4){0.f, 0.f, 0.f, 0.f};

    const int wr = wave >> 2;      // wave row (0..1): rows [wr*128, +128)
    const int wc = wave & 3;       // wave col (0..3): cols [wc*64, +64)
    const int half = lane >> 4;    // k-group
    const int lrow = lane & 15;

    const int row_me = tid >> 2;                       // 0..127
    const int kb_me  = (((tid & 3) ^ ((row_me >> 1) & 3)) << 4);

#define STAGE(bufidx, t) do {                                                              \
        int s0b = (t) * (BK * 2);                                                          \
        const char* gA0 = (const char*)Ap + (size_t)row_me * (S_ * 2) + s0b + kb_me;       \
        const char* gB0 = (const char*)Bp + (size_t)row_me * (S_ * 2) + s0b + kb_me;       \
        char* lA = (char*)(&sA[bufidx][0]) + tid * 16;                                     \
        char* lB = (char*)(&sB[bufidx][0]) + tid * 16;                                     \
        __builtin_amdgcn_global_load_lds((const __attribute__((address_space(1))) void*)gA0,                \
                                         (__attribute__((address_space(3))) void*)lA, 16, 0, 0);            \
        __builtin_amdgcn_global_load_lds((const __attribute__((address_space(1))) void*)(gA0 + 128*(S_*2)), \
                                         (__attribute__((address_space(3))) void*)(lA + 8192), 16, 0, 0);   \
        __builtin_amdgcn_global_load_lds((const __attribute__((address_space(1))) void*)gB0,                \
                                         (__attribute__((address_space(3))) void*)lB, 16, 0, 0);            \
        __builtin_amdgcn_global_load_lds((const __attribute__((address_space(1))) void*)(gB0 + 128*(S_*2)), \
                                         (__attribute__((address_space(3))) void*)(lB + 8192), 16, 0, 0);   \
    } while (0)

    STAGE(0, 0);
    asm volatile("s_waitcnt vmcnt(0)" ::: "memory");
    __syncthreads();

#pragma unroll 2
    for (int t = 0; t < NT; ++t) {
        const int cur = t & 1;
        if (t + 1 < NT) STAGE(cur ^ 1, t + 1);   // prefetch next K-slab

        const char* lA = (const char*)(&sA[cur][0]);
        const char* lB = (const char*)(&sB[cur][0]);
        bf16x8 af[8], bfr[4];
#pragma unroll
        for (int mI = 0; mI < 8; ++mI) {
            int row  = wr * 128 + mI * 16 + lrow;
            int byte = (row * 64 + half * 16) ^ (((row >> 1) & 3) << 4);
            af[mI] = *reinterpret_cast<const bf16x8*>(lA + byte);
        }
#pragma unroll
        for (int nI = 0; nI < 4; ++nI) {
            int row  = wc * 64 + nI * 16 + lrow;
            int byte = (row * 64 + half * 16) ^ (((row >> 1) & 3) << 4);
            bfr[nI] = *reinterpret_cast<const bf16x8*>(lB + byte);
        }
#pragma unroll
        for (int mI = 0; mI < 8; ++mI)
#pragma unroll
            for (int nI = 0; nI < 4; ++nI)
                acc[mI][nI] = __builtin_amdgcn_mfma_f32_16x16x32_bf16(af[mI], bfr[nI], acc[mI][nI], 0, 0, 0);

        __syncthreads();   // drains vmcnt+lgkmcnt (buffers safe to swap)
    }
#undef STAGE

    // C/D layout: col = lane&15 (from B), row = (lane>>4)*4 + reg (from A)
    __hip_bfloat16* Op = outer + (size_t)bc * (I_ * I_);
#pragma unroll
    for (int mI = 0; mI < 8; ++mI) {
        int ii = i0 + wr * 128 + mI * 16 + half * 4;
#pragma unroll
        for (int nI = 0; nI < 4; ++nI) {
            int jj = j0 + wc * 64 + nI * 16 + lrow;
#pragma unroll
            for (int r = 0; r < 4; ++r)
                Op[(size_t)(ii + r) * I_ + jj] =
                    __float2bfloat16(acc[mI][nI][r] * (1.f / S_));
        }
    }
}

// ---------------------------------------------------------------------------
// Pass 2: out[b,i,j,c] = bo[c] + sum_c' Wo[c,c'] * outer_scaled[(b,c'),i,j]
// outer is bf16 with 1/S pre-folded (L2/L3-resident from pass 1).
// ---------------------------------------------------------------------------
__global__ __launch_bounds__(256) void wo_kernel(
    const __hip_bfloat16* __restrict__ outer,
    const float* __restrict__ Wo, const float* __restrict__ bo,
    float* __restrict__ out)
{
    int tid = blockIdx.x * 256 + threadIdx.x;   // ((b*I + i)*J + j)
    int j  = tid & (I_ - 1);
    int bi = tid >> 9;
    int i  = bi & (I_ - 1);
    int b  = bi >> 9;

    const __hip_bfloat16* ip = outer + ((size_t)(b * C_) * I_ + i) * I_ + j;
    float v[C_];
#pragma unroll
    for (int c = 0; c < C_; ++c) v[c] = __bfloat162float(ip[(size_t)c * (I_ * I_)]);

    float o[C_];
#pragma unroll
    for (int c = 0; c < C_; ++c) {
        float acc = bo[c];
#pragma unroll
        for (int k = 0; k < C_; ++k) acc = fmaf(Wo[c * C_ + k], v[k], acc);
        o[c] = acc;
    }

    float* op = out + (size_t)tid * C_;
#pragma unroll
    for (int vv = 0; vv < 8; ++vv) {
        float4 t4 = { o[4*vv+0], o[4*vv+1], o[4*vv+2], o[4*vv+3] };
        reinterpret_cast<float4*>(op)[vv] = t4;
    }
}

// ---------------------------------------------------------------------------
extern "C" void kernel_launch(void* const* d_in, const int* in_sizes, int n_in,
                              void* d_out, int out_size, void* d_ws, size_t ws_size,
                              hipStream_t stream) {
    const float* m    = (const float*)d_in[0];
    const float* ln_g = (const float*)d_in[1];
    const float* ln_b = (const float*)d_in[2];
    const float* Wa   = (const float*)d_in[3];
    const float* ba   = (const float*)d_in[4];
    const float* Wb   = (const float*)d_in[5];
    const float* bb   = (const float*)d_in[6];
    const float* Wo   = (const float*)d_in[7];
    const float* bo   = (const float*)d_in[8];
    float* out = (float*)d_out;

    const size_t nAB = (size_t)B_ * C_ * PLST;      // padded planes
    const size_t nO  = (size_t)B_ * C_ * I_ * I_;   // 16,777,216 elems (32 MiB bf16)
    const size_t need = (nAB * 2 + nO) * sizeof(__hip_bfloat16);  // ~169 MB
    if (ws_size < need) return;   // diagnostic: output stays zero -> ws too small

    __hip_bfloat16* a_t = (__hip_bfloat16*)d_ws;
    __hip_bfloat16* b_t = a_t + nAB;
    __hip_bfloat16* outer = b_t + nAB;

    ln_proj_kernel<<<B_ * (I_ / 4) * (S_ / 64), 256, 0, stream>>>(m, ln_g, ln_b, Wa, ba, Wb, bb, a_t, b_t);
    opm_gemm_kernel<<<B_ * C_ * 4, 512, 0, stream>>>(a_t, b_t, outer);
    wo_kernel<<<(B_ * I_ * I_) / 256, 256, 0, stream>>>(outer, Wo, bo, out);
}